// Round 3
// baseline (2355.944 us; speedup 1.0000x reference)
//
#include <hip/hip_runtime.h>

// ---------------------------------------------------------------------------
// CapsuleNetwork: embedding -> 2-layer BiLSTM -> attn pooling -> routing
// Round 2 (resubmit; rounds 0-1 died to container infra failures, no data).
// All-fp32 correctness baseline.
// B=128 T=64 E=300 H=256 DA=128 R=8 SC=32 AT=16
// ---------------------------------------------------------------------------

__device__ __forceinline__ float sigf(float x) { return 1.0f / (1.0f + __expf(-x)); }
__device__ __forceinline__ float tanhf_fast(float x) { return 1.0f - 2.0f / (__expf(2.0f * x) + 1.0f); }

// ---------------- transpose w_hh [1024][256] -> Wt [256][1024] -------------
__global__ void k_transpose(const float* __restrict__ w0, const float* __restrict__ w1,
                            const float* __restrict__ w2, const float* __restrict__ w3,
                            float* __restrict__ wt)
{
    __shared__ float tile[32][33];
    const float* W = (blockIdx.z == 0) ? w0 : (blockIdx.z == 1) ? w1 : (blockIdx.z == 2) ? w2 : w3;
    float* Wt = wt + (size_t)blockIdx.z * 256 * 1024;
    const int j0 = blockIdx.x * 32, k0 = blockIdx.y * 32;
    const int tx = threadIdx.x, ty = threadIdx.y;  // (32,8)
    #pragma unroll
    for (int i = 0; i < 32; i += 8)
        tile[ty + i][tx] = W[(size_t)(j0 + ty + i) * 256 + (k0 + tx)];
    __syncthreads();
    #pragma unroll
    for (int i = 0; i < 32; i += 8)
        Wt[(size_t)(k0 + ty + i) * 1024 + (j0 + tx)] = tile[tx][ty + i];
}

// ---------------- generic fp32 GEMM ----------------------------------------
// C[m,n] = act( sum_k A[m,k]*W[n,k] + bias[n] )       (transb=1)
// C[m,n] = act( sum_k A[m,k]*W[k,n] + bias[n] )       (transb=0, K%16==0)
// Optional gather: row m of A = embedding[tokens[b*64+t]] with m = t*128+b.
// Tile 128x128, 256 threads, 8x8 microtile, TK=16.
// blockIdx.z strides A/W/C by sA/sW/sC (for per-r batched votes GEMM).
__global__ __launch_bounds__(256) void k_gemm(
    const float* __restrict__ A, int lda, const int* __restrict__ tokens,
    const float* __restrict__ W0, const float* __restrict__ W1, int nsplit, int ldw,
    const float* __restrict__ bias0, const float* __restrict__ bias1,
    float* __restrict__ C, int ldc, int K, int transb, int act_tanh,
    long long sA, long long sW, long long sC)
{
    __shared__ float As[16][128];
    __shared__ float Ws[16][128];
    A  += (size_t)blockIdx.z * (size_t)sA;
    W0 += (size_t)blockIdx.z * (size_t)sW;
    C  += (size_t)blockIdx.z * (size_t)sC;
    const int tid = threadIdx.x;
    const int m0 = blockIdx.x * 128;
    const int n0 = blockIdx.y * 128;

    // staging coords (transb==1 style): thread -> one row, 8 consecutive k
    const int srow = tid >> 1;
    const int kh   = (tid & 1) * 8;
    const int am = m0 + srow;
    const float* arow;
    if (tokens) {
        const int t = am >> 7, b = am & 127;
        arow = A + (size_t)tokens[b * 64 + t] * lda;
    } else {
        arow = A + (size_t)am * lda;
    }
    const int wn = n0 + srow;
    const float* wrow = (wn < nsplit) ? (W0 + (size_t)wn * ldw)
                                      : (W1 + (size_t)(wn - nsplit) * ldw);
    // transb==0 staging coords
    const int kw = tid & 15;
    const int n8 = (tid >> 4) * 8;

    const int tm = (tid & 15) * 8;
    const int tn = (tid >> 4) * 8;
    float acc[8][8] = {};

    for (int k0 = 0; k0 < K; k0 += 16) {
        // ---- stage A ----
        if (k0 + kh + 7 < K) {
            const float4 v0 = *(const float4*)(arow + k0 + kh);
            const float4 v1 = *(const float4*)(arow + k0 + kh + 4);
            As[kh + 0][srow] = v0.x; As[kh + 1][srow] = v0.y;
            As[kh + 2][srow] = v0.z; As[kh + 3][srow] = v0.w;
            As[kh + 4][srow] = v1.x; As[kh + 5][srow] = v1.y;
            As[kh + 6][srow] = v1.z; As[kh + 7][srow] = v1.w;
        } else {
            #pragma unroll
            for (int j = 0; j < 8; ++j)
                As[kh + j][srow] = (k0 + kh + j < K) ? arow[k0 + kh + j] : 0.0f;
        }
        // ---- stage W ----
        if (transb) {
            if (k0 + kh + 7 < K) {
                const float4 v0 = *(const float4*)(wrow + k0 + kh);
                const float4 v1 = *(const float4*)(wrow + k0 + kh + 4);
                Ws[kh + 0][srow] = v0.x; Ws[kh + 1][srow] = v0.y;
                Ws[kh + 2][srow] = v0.z; Ws[kh + 3][srow] = v0.w;
                Ws[kh + 4][srow] = v1.x; Ws[kh + 5][srow] = v1.y;
                Ws[kh + 6][srow] = v1.z; Ws[kh + 7][srow] = v1.w;
            } else {
                #pragma unroll
                for (int j = 0; j < 8; ++j)
                    Ws[kh + j][srow] = (k0 + kh + j < K) ? wrow[k0 + kh + j] : 0.0f;
            }
        } else {
            const float* src = W0 + (size_t)(k0 + kw) * ldw + n0 + n8;
            *(float4*)&Ws[kw][n8]     = *(const float4*)(src);
            *(float4*)&Ws[kw][n8 + 4] = *(const float4*)(src + 4);
        }
        __syncthreads();
        #pragma unroll
        for (int kk = 0; kk < 16; ++kk) {
            const float4 a0 = *(const float4*)&As[kk][tm];
            const float4 a1 = *(const float4*)&As[kk][tm + 4];
            const float4 b0 = *(const float4*)&Ws[kk][tn];
            const float4 b1 = *(const float4*)&Ws[kk][tn + 4];
            const float av[8] = {a0.x, a0.y, a0.z, a0.w, a1.x, a1.y, a1.z, a1.w};
            const float bv[8] = {b0.x, b0.y, b0.z, b0.w, b1.x, b1.y, b1.z, b1.w};
            #pragma unroll
            for (int i = 0; i < 8; ++i)
                #pragma unroll
                for (int j = 0; j < 8; ++j)
                    acc[i][j] += av[i] * bv[j];
        }
        __syncthreads();
    }
    // ---- epilogue ----
    const int half = (n0 >= nsplit) ? 1 : 0;
    const float* bp = half ? bias1 : bias0;
    const int nl = n0 - (half ? nsplit : 0);
    #pragma unroll
    for (int i = 0; i < 8; ++i) {
        float v[8];
        #pragma unroll
        for (int j = 0; j < 8; ++j) {
            float x = acc[i][j];
            if (bp) x += bp[nl + tn + j];
            if (act_tanh) x = tanhf_fast(x);
            v[j] = x;
        }
        float* crow = C + (size_t)(m0 + tm + i) * ldc + n0 + tn;
        *(float4*)(crow)     = make_float4(v[0], v[1], v[2], v[3]);
        *(float4*)(crow + 4) = make_float4(v[4], v[5], v[6], v[7]);
    }
}

// ---------------- persistent BiLSTM scan -----------------------------------
// Grid: 64 blocks (32 fwd + 32 bwd), 512 threads. Block owns 4 batch rows,
// loops all 64 timesteps (recurrence is batch-local -> no grid sync).
// Zin [8192][2048] holds precomputed x@W_ih^T + bias (cols 0..1023 fwd dir).
// Wt [256][1024] transposed recurrent weights, streamed from L2 each step.
// out [8192][512]: row = t*128+b (bt_layout=0) or b*64+t (bt_layout=1),
//                  cols 0..255 fwd h, 256..511 bwd h.
__global__ __launch_bounds__(512) void k_scan(
    const float* __restrict__ Zin,
    const float* __restrict__ WtF, const float* __restrict__ WtB,
    float* __restrict__ outbuf, int bt_layout)
{
    __shared__ float h_lds[4][256];
    __shared__ float z_lds[4][1024];
    __shared__ float red[2][4][1024];   // 52 KB total static LDS

    const int tid = threadIdx.x;
    const int dir = blockIdx.x >> 5;
    const int b0  = (blockIdx.x & 31) * 4;
    const float* __restrict__ Wt = dir ? WtB : WtF;
    const float* __restrict__ Zb = Zin + dir * 1024;

    const int ks = tid >> 7;            // 0..3 : k-range split
    const int jb = tid & 127;           // 0..127: 8 output cols each
    const int colbase = jb * 8;
    const int pb0 = tid >> 8,          pk0 = tid & 255;          // phase2 pair 0
    const int pb1 = (tid + 512) >> 8,  pk1 = (tid + 512) & 255;  // phase2 pair 1
    float c0 = 0.0f, c1 = 0.0f;

    h_lds[pb0][pk0] = 0.0f;
    h_lds[pb1][pk1] = 0.0f;
    __syncthreads();

    const float* wbase = Wt + (size_t)(ks * 64) * 1024 + colbase;

    for (int tt = 0; tt < 64; ++tt) {
        const int t = dir ? (63 - tt) : tt;
        // ---- phase 1: partial dot z[b][col] += sum_{k in ks-range} h[b][k]*Wt[k][col]
        float acc[4][8] = {};
        #pragma unroll 4
        for (int k4 = 0; k4 < 64; k4 += 4) {
            const int kg = (ks << 6) + k4;
            float hq[4][4];
            #pragma unroll
            for (int b = 0; b < 4; ++b) {
                const float4 hv = *(const float4*)&h_lds[b][kg];
                hq[b][0] = hv.x; hq[b][1] = hv.y; hq[b][2] = hv.z; hq[b][3] = hv.w;
            }
            #pragma unroll
            for (int dk = 0; dk < 4; ++dk) {
                const float4 wA = *(const float4*)(wbase + (size_t)(k4 + dk) * 1024);
                const float4 wB = *(const float4*)(wbase + (size_t)(k4 + dk) * 1024 + 4);
                const float wv[8] = {wA.x, wA.y, wA.z, wA.w, wB.x, wB.y, wB.z, wB.w};
                #pragma unroll
                for (int b = 0; b < 4; ++b) {
                    const float hvb = hq[b][dk];
                    #pragma unroll
                    for (int j = 0; j < 8; ++j) acc[b][j] += hvb * wv[j];
                }
            }
        }
        // ---- reduction: ks1->red0, ks2->red1, ks3->z_lds; ks0 combines
        if (ks == 1) {
            #pragma unroll
            for (int b = 0; b < 4; ++b) {
                *(float4*)&red[0][b][colbase]     = make_float4(acc[b][0], acc[b][1], acc[b][2], acc[b][3]);
                *(float4*)&red[0][b][colbase + 4] = make_float4(acc[b][4], acc[b][5], acc[b][6], acc[b][7]);
            }
        } else if (ks == 2) {
            #pragma unroll
            for (int b = 0; b < 4; ++b) {
                *(float4*)&red[1][b][colbase]     = make_float4(acc[b][0], acc[b][1], acc[b][2], acc[b][3]);
                *(float4*)&red[1][b][colbase + 4] = make_float4(acc[b][4], acc[b][5], acc[b][6], acc[b][7]);
            }
        } else if (ks == 3) {
            #pragma unroll
            for (int b = 0; b < 4; ++b) {
                *(float4*)&z_lds[b][colbase]     = make_float4(acc[b][0], acc[b][1], acc[b][2], acc[b][3]);
                *(float4*)&z_lds[b][colbase + 4] = make_float4(acc[b][4], acc[b][5], acc[b][6], acc[b][7]);
            }
        }
        __syncthreads();
        if (ks == 0) {
            #pragma unroll
            for (int b = 0; b < 4; ++b) {
                const float4 r0 = *(const float4*)&red[0][b][colbase];
                const float4 r1 = *(const float4*)&red[0][b][colbase + 4];
                const float4 r2 = *(const float4*)&red[1][b][colbase];
                const float4 r3 = *(const float4*)&red[1][b][colbase + 4];
                const float4 r4 = *(const float4*)&z_lds[b][colbase];
                const float4 r5 = *(const float4*)&z_lds[b][colbase + 4];
                acc[b][0] += r0.x + r2.x + r4.x; acc[b][1] += r0.y + r2.y + r4.y;
                acc[b][2] += r0.z + r2.z + r4.z; acc[b][3] += r0.w + r2.w + r4.w;
                acc[b][4] += r1.x + r3.x + r5.x; acc[b][5] += r1.y + r3.y + r5.y;
                acc[b][6] += r1.z + r3.z + r5.z; acc[b][7] += r1.w + r3.w + r5.w;
                *(float4*)&z_lds[b][colbase]     = make_float4(acc[b][0], acc[b][1], acc[b][2], acc[b][3]);
                *(float4*)&z_lds[b][colbase + 4] = make_float4(acc[b][4], acc[b][5], acc[b][6], acc[b][7]);
            }
        }
        __syncthreads();
        // ---- phase 2: gates, state update, h out (2 (b,k) pairs/thread)
        {
            const float* zrow0 = Zb + (size_t)((t << 7) + b0 + pb0) * 2048;
            const float zi = z_lds[pb0][pk0]       + zrow0[pk0];
            const float zf = z_lds[pb0][256 + pk0] + zrow0[256 + pk0];
            const float zg = z_lds[pb0][512 + pk0] + zrow0[512 + pk0];
            const float zo = z_lds[pb0][768 + pk0] + zrow0[768 + pk0];
            const float gi = sigf(zi), gf = sigf(zf), gg = tanhf_fast(zg), go = sigf(zo);
            c0 = gf * c0 + gi * gg;
            const float h = go * tanhf_fast(c0);
            h_lds[pb0][pk0] = h;
            const int row = bt_layout ? (((b0 + pb0) << 6) + t) : ((t << 7) + b0 + pb0);
            outbuf[(size_t)row * 512 + (dir << 8) + pk0] = h;
        }
        {
            const float* zrow1 = Zb + (size_t)((t << 7) + b0 + pb1) * 2048;
            const float zi = z_lds[pb1][pk1]       + zrow1[pk1];
            const float zf = z_lds[pb1][256 + pk1] + zrow1[256 + pk1];
            const float zg = z_lds[pb1][512 + pk1] + zrow1[512 + pk1];
            const float zo = z_lds[pb1][768 + pk1] + zrow1[768 + pk1];
            const float gi = sigf(zi), gf = sigf(zf), gg = tanhf_fast(zg), go = sigf(zo);
            c1 = gf * c1 + gi * gg;
            const float h = go * tanhf_fast(c1);
            h_lds[pb1][pk1] = h;
            const int row = bt_layout ? (((b0 + pb1) << 6) + t) : ((t << 7) + b0 + pb1);
            outbuf[(size_t)row * 512 + (dir << 8) + pk1] = h;
        }
        __syncthreads();
    }
}

// ---------------- attention pooling (fused att + sent) ---------------------
// One block per batch b. hbar [8192][128] rows b*64+t ; outp [8192][512].
// att[r,t] = sum_d hbar[b,t,d]*ws2[r,d];  sent[b,r,u] = sum_t att[r,t]*outp[b,t,u]
__global__ __launch_bounds__(256) void k_attnpool(
    const float* __restrict__ hbar, const float* __restrict__ outp,
    const float* __restrict__ ws2, float* __restrict__ sent)
{
    __shared__ float hb[64][132];
    __shared__ float w2[8][128];
    __shared__ float att[8][64];
    const int b = blockIdx.x, tid = threadIdx.x;
    for (int i = tid; i < 1024; i += 256) ((float*)w2)[i] = ws2[i];
    const float* hsrc = hbar + (size_t)b * 64 * 128;
    for (int i = tid; i < 2048; i += 256) {
        const int row = i >> 5, d4 = (i & 31) << 2;
        *(float4*)&hb[row][d4] = *(const float4*)(hsrc + row * 128 + d4);
    }
    __syncthreads();
    for (int p = tid; p < 512; p += 256) {
        const int r = p >> 6, t = p & 63;
        float s = 0.0f;
        #pragma unroll 8
        for (int d = 0; d < 128; d += 4) {
            const float4 x = *(const float4*)&hb[t][d];
            const float4 y = *(const float4*)&w2[r][d];
            s += x.x * y.x + x.y * y.y + x.z * y.z + x.w * y.w;
        }
        att[r][t] = s;
    }
    __syncthreads();
    const float* ob = outp + (size_t)b * 64 * 512;
    float s0[8] = {}, s1[8] = {};
    for (int t = 0; t < 64; ++t) {
        const float v0 = ob[t * 512 + tid];
        const float v1 = ob[t * 512 + 256 + tid];
        #pragma unroll
        for (int r = 0; r < 8; ++r) {
            const float a = att[r][t];
            s0[r] += a * v0; s1[r] += a * v1;
        }
    }
    #pragma unroll
    for (int r = 0; r < 8; ++r) {
        sent[((size_t)b * 8 + r) * 512 + tid]       = s0[r];
        sent[((size_t)b * 8 + r) * 512 + 256 + tid] = s1[r];
    }
}

// ---------------- dynamic routing ------------------------------------------
// One block per b, 512 threads = (c=32) x (a=16). votes [128][8][512].
__global__ __launch_bounds__(512) void k_routing(
    const float* __restrict__ votes, float* __restrict__ out)
{
    __shared__ float v[8][32][16];
    __shared__ float logits[8][32];
    __shared__ float route[8][32];
    const int b = blockIdx.x, tid = threadIdx.x;
    const float* vb = votes + (size_t)b * 4096;
    for (int i = tid; i < 4096; i += 512) ((float*)v)[i] = vb[i];
    if (tid < 256) ((float*)logits)[tid] = 0.0f;
    __syncthreads();
    const int c = tid >> 4, a = tid & 15;
    float nrm = 0.0f, n2 = 0.0f;
    for (int it = 0; it < 3; ++it) {
        if (tid < 256) {
            const int r = tid >> 5, cc = tid & 31;
            const float l = logits[r][cc];
            float mx = l;
            #pragma unroll
            for (int m = 1; m < 32; m <<= 1) mx = fmaxf(mx, __shfl_xor(mx, m));
            const float e = __expf(l - mx);
            float s = e;
            #pragma unroll
            for (int m = 1; m < 32; m <<= 1) s += __shfl_xor(s, m);
            route[r][cc] = e / s;
        }
        __syncthreads();
        float pa = 0.0f;
        #pragma unroll
        for (int r = 0; r < 8; ++r) pa += route[r][c] * v[r][c][a];
        n2 = pa * pa;
        #pragma unroll
        for (int m = 1; m < 16; m <<= 1) n2 += __shfl_xor(n2, m);
        nrm = sqrtf(n2);
        const float av = pa * (nrm / (0.5f + n2));
        if (it < 2) {
            #pragma unroll
            for (int r = 0; r < 8; ++r) {
                float u = v[r][c][a] * av;
                #pragma unroll
                for (int m = 1; m < 16; m <<= 1) u += __shfl_xor(u, m);
                if (a == 0) logits[r][c] += u;
            }
        }
        __syncthreads();
    }
    // ||act|| = ||preact|| * nrm/(0.5+n2) = n2/(0.5+n2)
    if (a == 0) out[b * 32 + c] = n2 / (0.5f + n2);
}

// ---------------------------------------------------------------------------
extern "C" void kernel_launch(void* const* d_in, const int* in_sizes, int n_in,
                              void* d_out, int out_size, void* d_ws, size_t ws_size,
                              hipStream_t stream) {
    (void)in_sizes; (void)n_in; (void)out_size; (void)ws_size;
    const int*   tokens  = (const int*)d_in[0];
    const float* emb     = (const float*)d_in[2];
    const float* w_ih_f0 = (const float*)d_in[3];
    const float* w_hh_f0 = (const float*)d_in[4];
    const float* b_f0    = (const float*)d_in[5];
    const float* w_ih_b0 = (const float*)d_in[6];
    const float* w_hh_b0 = (const float*)d_in[7];
    const float* b_b0    = (const float*)d_in[8];
    const float* w_ih_f1 = (const float*)d_in[9];
    const float* w_hh_f1 = (const float*)d_in[10];
    const float* b_f1    = (const float*)d_in[11];
    const float* w_ih_b1 = (const float*)d_in[12];
    const float* w_hh_b1 = (const float*)d_in[13];
    const float* b_b1    = (const float*)d_in[14];
    const float* ws1     = (const float*)d_in[15];
    const float* ws2     = (const float*)d_in[16];
    const float* caps    = (const float*)d_in[17];

    float* wsf  = (float*)d_ws;
    float* Wt   = wsf;                          //  4 * 262144      (4.2 MB)
    float* Z    = Wt   + 4 * 262144;            //  8192*2048       (67 MB)
    float* x1   = Z    + 16777216;              //  8192*512        (16.8 MB)
    float* outp = x1   + 4194304;               //  8192*512        (16.8 MB)
    float* hbar = outp + 4194304;               //  8192*128        (4.2 MB)
    float* sent = hbar + 1048576;               //  128*8*512       (2.1 MB)
    float* vote = sent + 524288;                //  128*8*512       (2.1 MB)
    float* out  = (float*)d_out;

    // 1. transpose recurrent weights
    k_transpose<<<dim3(32, 8, 4), dim3(32, 8), 0, stream>>>(w_hh_f0, w_hh_b0, w_hh_f1, w_hh_b1, Wt);
    // 2. layer-0 input projection (embedding gather fused), Z[.,0:1024]=fwd, [.,1024:2048]=bwd
    k_gemm<<<dim3(64, 16, 1), 256, 0, stream>>>(
        emb, 300, tokens, w_ih_f0, w_ih_b0, 1024, 300, b_f0, b_b0,
        Z, 2048, 300, 1, 0, 0LL, 0LL, 0LL);
    // 3. layer-0 scan -> x1 [t*128+b][512]
    k_scan<<<dim3(64), 512, 0, stream>>>(Z, Wt, Wt + 262144, x1, 0);
    // 4. layer-1 input projection
    k_gemm<<<dim3(64, 16, 1), 256, 0, stream>>>(
        x1, 512, (const int*)nullptr, w_ih_f1, w_ih_b1, 1024, 512, b_f1, b_b1,
        Z, 2048, 512, 1, 0, 0LL, 0LL, 0LL);
    // 5. layer-1 scan -> outp [b*64+t][512]
    k_scan<<<dim3(64), 512, 0, stream>>>(Z, Wt + 2 * 262144, Wt + 3 * 262144, outp, 1);
    // 6. hbar = tanh(outp @ ws1^T)  [8192][128]
    k_gemm<<<dim3(64, 1, 1), 256, 0, stream>>>(
        outp, 512, (const int*)nullptr, ws1, (const float*)nullptr, 1 << 30, 512,
        (const float*)nullptr, (const float*)nullptr,
        hbar, 128, 512, 1, 1, 0LL, 0LL, 0LL);
    // 7. attention + sent
    k_attnpool<<<dim3(128), 256, 0, stream>>>(hbar, outp, ws2, sent);
    // 8. votes[b,r,:] = sent[b,r,:] @ caps_w[r]   (per-r via blockIdx.z)
    k_gemm<<<dim3(1, 4, 8), 256, 0, stream>>>(
        sent, 4096, (const int*)nullptr, caps, (const float*)nullptr, 1 << 30, 512,
        (const float*)nullptr, (const float*)nullptr,
        vote, 4096, 512, 0, 0, 512LL, 262144LL, 512LL);
    // 9. dynamic routing + class logits
    k_routing<<<dim3(128), 512, 0, stream>>>(vote, out);
}

// Round 4
// 1606.312 us; speedup vs baseline: 1.4667x; 1.4667x over previous
//
#include <hip/hip_runtime.h>

// ---------------------------------------------------------------------------
// CapsuleNetwork: embedding -> 2-layer BiLSTM -> attn pooling -> routing
// Round 3: rewrite BiLSTM scan for full-chip occupancy + stationary weights.
//   - 256 blocks x 512 thr (1/CU), W-slice in VGPRs (128/thread, loaded once)
//   - h in LDS (XOR-swizzled), 16-way k-split + DPP butterfly reduce
//   - cross-block h exchange via agent-scope atomics + per-step flags (IF$)
// B=128 T=64 E=300 H=256 DA=128 R=8 SC=32 AT=16
// ---------------------------------------------------------------------------

__device__ __forceinline__ float sigf(float x) { return 1.0f / (1.0f + __expf(-x)); }
__device__ __forceinline__ float tanhf_fast(float x) { return 1.0f - 2.0f / (__expf(2.0f * x) + 1.0f); }

#define DPPF(v, ctrl) __int_as_float(__builtin_amdgcn_update_dpp(0, __float_as_int(v), ctrl, 0xF, 0xF, true))

// ---------------- transpose w_hh [1024][256] -> Wt [256][1024] -------------
__global__ void k_transpose(const float* __restrict__ w0, const float* __restrict__ w1,
                            const float* __restrict__ w2, const float* __restrict__ w3,
                            float* __restrict__ wt)
{
    __shared__ float tile[32][33];
    const float* W = (blockIdx.z == 0) ? w0 : (blockIdx.z == 1) ? w1 : (blockIdx.z == 2) ? w2 : w3;
    float* Wt = wt + (size_t)blockIdx.z * 256 * 1024;
    const int j0 = blockIdx.x * 32, k0 = blockIdx.y * 32;
    const int tx = threadIdx.x, ty = threadIdx.y;  // (32,8)
    #pragma unroll
    for (int i = 0; i < 32; i += 8)
        tile[ty + i][tx] = W[(size_t)(j0 + ty + i) * 256 + (k0 + tx)];
    __syncthreads();
    #pragma unroll
    for (int i = 0; i < 32; i += 8)
        Wt[(size_t)(k0 + ty + i) * 1024 + (j0 + tx)] = tile[tx][ty + i];
}

// ---------------- zero sync flags ------------------------------------------
__global__ void k_zero(int* __restrict__ p, int n)
{
    const int i = blockIdx.x * blockDim.x + threadIdx.x;
    if (i < n) p[i] = 0;
}

// ---------------- generic fp32 GEMM (unchanged from baseline) --------------
__global__ __launch_bounds__(256) void k_gemm(
    const float* __restrict__ A, int lda, const int* __restrict__ tokens,
    const float* __restrict__ W0, const float* __restrict__ W1, int nsplit, int ldw,
    const float* __restrict__ bias0, const float* __restrict__ bias1,
    float* __restrict__ C, int ldc, int K, int transb, int act_tanh,
    long long sA, long long sW, long long sC)
{
    __shared__ float As[16][128];
    __shared__ float Ws[16][128];
    A  += (size_t)blockIdx.z * (size_t)sA;
    W0 += (size_t)blockIdx.z * (size_t)sW;
    C  += (size_t)blockIdx.z * (size_t)sC;
    const int tid = threadIdx.x;
    const int m0 = blockIdx.x * 128;
    const int n0 = blockIdx.y * 128;

    const int srow = tid >> 1;
    const int kh   = (tid & 1) * 8;
    const int am = m0 + srow;
    const float* arow;
    if (tokens) {
        const int t = am >> 7, b = am & 127;
        arow = A + (size_t)tokens[b * 64 + t] * lda;
    } else {
        arow = A + (size_t)am * lda;
    }
    const int wn = n0 + srow;
    const float* wrow = (wn < nsplit) ? (W0 + (size_t)wn * ldw)
                                      : (W1 + (size_t)(wn - nsplit) * ldw);
    const int kw = tid & 15;
    const int n8 = (tid >> 4) * 8;

    const int tm = (tid & 15) * 8;
    const int tn = (tid >> 4) * 8;
    float acc[8][8] = {};

    for (int k0 = 0; k0 < K; k0 += 16) {
        if (k0 + kh + 7 < K) {
            const float4 v0 = *(const float4*)(arow + k0 + kh);
            const float4 v1 = *(const float4*)(arow + k0 + kh + 4);
            As[kh + 0][srow] = v0.x; As[kh + 1][srow] = v0.y;
            As[kh + 2][srow] = v0.z; As[kh + 3][srow] = v0.w;
            As[kh + 4][srow] = v1.x; As[kh + 5][srow] = v1.y;
            As[kh + 6][srow] = v1.z; As[kh + 7][srow] = v1.w;
        } else {
            #pragma unroll
            for (int j = 0; j < 8; ++j)
                As[kh + j][srow] = (k0 + kh + j < K) ? arow[k0 + kh + j] : 0.0f;
        }
        if (transb) {
            if (k0 + kh + 7 < K) {
                const float4 v0 = *(const float4*)(wrow + k0 + kh);
                const float4 v1 = *(const float4*)(wrow + k0 + kh + 4);
                Ws[kh + 0][srow] = v0.x; Ws[kh + 1][srow] = v0.y;
                Ws[kh + 2][srow] = v0.z; Ws[kh + 3][srow] = v0.w;
                Ws[kh + 4][srow] = v1.x; Ws[kh + 5][srow] = v1.y;
                Ws[kh + 6][srow] = v1.z; Ws[kh + 7][srow] = v1.w;
            } else {
                #pragma unroll
                for (int j = 0; j < 8; ++j)
                    Ws[kh + j][srow] = (k0 + kh + j < K) ? wrow[k0 + kh + j] : 0.0f;
            }
        } else {
            const float* src = W0 + (size_t)(k0 + kw) * ldw + n0 + n8;
            *(float4*)&Ws[kw][n8]     = *(const float4*)(src);
            *(float4*)&Ws[kw][n8 + 4] = *(const float4*)(src + 4);
        }
        __syncthreads();
        #pragma unroll
        for (int kk = 0; kk < 16; ++kk) {
            const float4 a0 = *(const float4*)&As[kk][tm];
            const float4 a1 = *(const float4*)&As[kk][tm + 4];
            const float4 b0 = *(const float4*)&Ws[kk][tn];
            const float4 b1 = *(const float4*)&Ws[kk][tn + 4];
            const float av[8] = {a0.x, a0.y, a0.z, a0.w, a1.x, a1.y, a1.z, a1.w};
            const float bv[8] = {b0.x, b0.y, b0.z, b0.w, b1.x, b1.y, b1.z, b1.w};
            #pragma unroll
            for (int i = 0; i < 8; ++i)
                #pragma unroll
                for (int j = 0; j < 8; ++j)
                    acc[i][j] += av[i] * bv[j];
        }
        __syncthreads();
    }
    const int half = (n0 >= nsplit) ? 1 : 0;
    const float* bp = half ? bias1 : bias0;
    const int nl = n0 - (half ? nsplit : 0);
    #pragma unroll
    for (int i = 0; i < 8; ++i) {
        float v[8];
        #pragma unroll
        for (int j = 0; j < 8; ++j) {
            float x = acc[i][j];
            if (bp) x += bp[nl + tn + j];
            if (act_tanh) x = tanhf_fast(x);
            v[j] = x;
        }
        float* crow = C + (size_t)(m0 + tm + i) * ldc + n0 + tn;
        *(float4*)(crow)     = make_float4(v[0], v[1], v[2], v[3]);
        *(float4*)(crow + 4) = make_float4(v[4], v[5], v[6], v[7]);
    }
}

// ---------------- full-chip BiLSTM scan ------------------------------------
// 256 blocks x 512 threads. blockIdx: s = bx>>6 (dim slice 0..3),
// q = bx&63 (sync group: dir = q>>5, gq = q&31 -> 4 batch rows).
// Group members are bx = q + 64*s -> same bx%8 -> same XCD (heuristic only;
// correctness uses agent-scope atomics regardless).
// Thread: ow = tid>>4 (owns 8 z-cols), ks = tid&15 (k-chunk of 16).
// W-slice in VGPRs: W[16][8] per thread. h in LDS, XOR-swizzled.
// Per step: phase1 partial GEMM -> DPP butterfly over 16 lanes -> zbuf;
// phase2 (tid<256): gates + c/h update; h -> out, hx (agent), flag++.
__global__ __launch_bounds__(512, 2) void k_scan2(
    const float* __restrict__ Zin, const float* __restrict__ WtF,
    const float* __restrict__ WtB, float* __restrict__ outbuf,
    int bt_layout, float* __restrict__ hx, int* __restrict__ flags)
{
    __shared__ __align__(16) float hbuf[1024];
    __shared__ float zbuf[1024];

    const int bx  = blockIdx.x;
    const int s   = bx >> 6;
    const int q   = bx & 63;
    const int dir = q >> 5;
    const int gq  = q & 31;
    const int tid = threadIdx.x;
    const int ow  = tid >> 4;
    const int ks  = tid & 15;
    const float* __restrict__ Wt = dir ? WtB : WtF;

    // ---- preload W slice into registers (once) ----
    const int gate    = ow >> 3;
    const int colbase = gate * 256 + s * 64 + (ow & 7) * 8;
    float W[16][8];
    {
        const float* wp = Wt + (size_t)(ks * 16) * 1024 + colbase;
        #pragma unroll
        for (int i = 0; i < 16; ++i) {
            const float4 wa = *(const float4*)(wp + (size_t)i * 1024);
            const float4 wb = *(const float4*)(wp + (size_t)i * 1024 + 4);
            W[i][0] = wa.x; W[i][1] = wa.y; W[i][2] = wa.z; W[i][3] = wa.w;
            W[i][4] = wb.x; W[i][5] = wb.y; W[i][6] = wb.z; W[i][7] = wb.w;
        }
    }

    const int p2b = (tid >> 6) & 3;
    const int p2d = tid & 63;
    const int dim = s * 64 + p2d;
    const int gb  = gq * 4 + p2b;
    float c_state = 0.0f;
    const int fbase = q * 64;

    for (int tt = 0; tt < 64; ++tt) {
        const int t = dir ? (63 - tt) : tt;
        // Zin prefetch (independent of h; overlaps staging + phase1)
        float z0 = 0.f, z1 = 0.f, z2 = 0.f, z3 = 0.f;
        if (tid < 256) {
            const float* zr = Zin + (size_t)(t * 128 + gb) * 2048 + dir * 1024 + dim;
            z0 = zr[0]; z1 = zr[256]; z2 = zr[512]; z3 = zr[768];
        }
        if (tt > 0) {
            // ---- wait for all 4 slice-blocks to publish h(tt-1) ----
            if (tid == 0) {
                while (__hip_atomic_load(&flags[fbase + tt - 1], __ATOMIC_ACQUIRE,
                                         __HIP_MEMORY_SCOPE_AGENT) < 4)
                    __builtin_amdgcn_s_sleep(1);
            }
            __syncthreads();
            // ---- stage h(tt-1) from IF$ into LDS (XOR-swizzled [k][4b]) ----
            {
                const float* hsrc = hx + ((((size_t)((tt - 1) & 1)) * 2 + dir) * 32 + gq) * 1024;
                #pragma unroll
                for (int j = 0; j < 2; ++j) {
                    const int idx = j * 512 + tid;
                    const int b = idx & 3, d = (idx >> 2) & 255;
                    const float v = __hip_atomic_load(&hsrc[b * 256 + d], __ATOMIC_RELAXED,
                                                      __HIP_MEMORY_SCOPE_AGENT);
                    hbuf[((d << 2) ^ (((d >> 4) & 7) << 2)) + b] = v;
                }
            }
            __syncthreads();
            // ---- phase 1: z_partial[4b][8c] over 16-k chunk (W in regs) ----
            float acc[4][8] = {};
            #pragma unroll
            for (int i = 0; i < 16; ++i) {
                const int k = ks * 16 + i;
                const float4 h4 = *(const float4*)&hbuf[(k << 2) ^ (((k >> 4) & 7) << 2)];
                const float hv[4] = {h4.x, h4.y, h4.z, h4.w};
                #pragma unroll
                for (int c = 0; c < 8; ++c)
                    #pragma unroll
                    for (int b = 0; b < 4; ++b)
                        acc[b][c] += hv[b] * W[i][c];
            }
            // ---- DPP butterfly sum over the 16 ks-lanes (row-aligned) ----
            #pragma unroll
            for (int b = 0; b < 4; ++b)
                #pragma unroll
                for (int c = 0; c < 8; ++c) {
                    float v = acc[b][c];
                    v += DPPF(v, 0xB1);                  // xor 1 (quad_perm)
                    v += DPPF(v, 0x4E);                  // xor 2 (quad_perm)
                    v += DPPF(DPPF(v, 0x141), 0x1B);     // xor 4 (half_mirror+reverse)
                    v += DPPF(v, 0x128);                 // xor 8 (row_ror:8)
                    acc[b][c] = v;
                }
            // lane ks writes elements a = 2ks, 2ks+1 (static idx, predicated)
            #pragma unroll
            for (int a = 0; a < 32; ++a)
                if (ks == (a >> 1))
                    zbuf[(a >> 3) * 256 + ow * 8 + (a & 7)] = acc[a >> 3][a & 7];
            __syncthreads();
        } else {
            zbuf[tid] = 0.0f;
            zbuf[512 + tid] = 0.0f;
            __syncthreads();
        }
        // ---- phase 2: gates, state update, publish h ----
        if (tid < 256) {
            const float zi = zbuf[p2b * 256 +       p2d] + z0;
            const float zf = zbuf[p2b * 256 +  64 + p2d] + z1;
            const float zg = zbuf[p2b * 256 + 128 + p2d] + z2;
            const float zo = zbuf[p2b * 256 + 192 + p2d] + z3;
            c_state = sigf(zf) * c_state + sigf(zi) * tanhf_fast(zg);
            const float h = sigf(zo) * tanhf_fast(c_state);
            const int row = bt_layout ? (gb * 64 + t) : (t * 128 + gb);
            outbuf[(size_t)row * 512 + dir * 256 + dim] = h;
            __hip_atomic_store(
                &hx[(((size_t)(tt & 1)) * 2 + dir) * 32768 + (size_t)gq * 1024 + p2b * 256 + dim],
                h, __ATOMIC_RELAXED, __HIP_MEMORY_SCOPE_AGENT);
        }
        __syncthreads();  // drains all waves' stores (vmcnt 0 before barrier)
        if (tid == 0)
            __hip_atomic_fetch_add(&flags[fbase + tt], 1, __ATOMIC_RELEASE,
                                   __HIP_MEMORY_SCOPE_AGENT);
    }
}

// ---------------- attention pooling (unchanged) ----------------------------
__global__ __launch_bounds__(256) void k_attnpool(
    const float* __restrict__ hbar, const float* __restrict__ outp,
    const float* __restrict__ ws2, float* __restrict__ sent)
{
    __shared__ float hb[64][132];
    __shared__ float w2[8][128];
    __shared__ float att[8][64];
    const int b = blockIdx.x, tid = threadIdx.x;
    for (int i = tid; i < 1024; i += 256) ((float*)w2)[i] = ws2[i];
    const float* hsrc = hbar + (size_t)b * 64 * 128;
    for (int i = tid; i < 2048; i += 256) {
        const int row = i >> 5, d4 = (i & 31) << 2;
        *(float4*)&hb[row][d4] = *(const float4*)(hsrc + row * 128 + d4);
    }
    __syncthreads();
    for (int p = tid; p < 512; p += 256) {
        const int r = p >> 6, t = p & 63;
        float s = 0.0f;
        #pragma unroll 8
        for (int d = 0; d < 128; d += 4) {
            const float4 x = *(const float4*)&hb[t][d];
            const float4 y = *(const float4*)&w2[r][d];
            s += x.x * y.x + x.y * y.y + x.z * y.z + x.w * y.w;
        }
        att[r][t] = s;
    }
    __syncthreads();
    const float* ob = outp + (size_t)b * 64 * 512;
    float s0[8] = {}, s1[8] = {};
    for (int t = 0; t < 64; ++t) {
        const float v0 = ob[t * 512 + tid];
        const float v1 = ob[t * 512 + 256 + tid];
        #pragma unroll
        for (int r = 0; r < 8; ++r) {
            const float a = att[r][t];
            s0[r] += a * v0; s1[r] += a * v1;
        }
    }
    #pragma unroll
    for (int r = 0; r < 8; ++r) {
        sent[((size_t)b * 8 + r) * 512 + tid]       = s0[r];
        sent[((size_t)b * 8 + r) * 512 + 256 + tid] = s1[r];
    }
}

// ---------------- dynamic routing (unchanged) ------------------------------
__global__ __launch_bounds__(512) void k_routing(
    const float* __restrict__ votes, float* __restrict__ out)
{
    __shared__ float v[8][32][16];
    __shared__ float logits[8][32];
    __shared__ float route[8][32];
    const int b = blockIdx.x, tid = threadIdx.x;
    const float* vb = votes + (size_t)b * 4096;
    for (int i = tid; i < 4096; i += 512) ((float*)v)[i] = vb[i];
    if (tid < 256) ((float*)logits)[tid] = 0.0f;
    __syncthreads();
    const int c = tid >> 4, a = tid & 15;
    float n2 = 0.0f;
    for (int it = 0; it < 3; ++it) {
        if (tid < 256) {
            const int r = tid >> 5, cc = tid & 31;
            const float l = logits[r][cc];
            float mx = l;
            #pragma unroll
            for (int m = 1; m < 32; m <<= 1) mx = fmaxf(mx, __shfl_xor(mx, m));
            const float e = __expf(l - mx);
            float sm = e;
            #pragma unroll
            for (int m = 1; m < 32; m <<= 1) sm += __shfl_xor(sm, m);
            route[r][cc] = e / sm;
        }
        __syncthreads();
        float pa = 0.0f;
        #pragma unroll
        for (int r = 0; r < 8; ++r) pa += route[r][c] * v[r][c][a];
        n2 = pa * pa;
        #pragma unroll
        for (int m = 1; m < 16; m <<= 1) n2 += __shfl_xor(n2, m);
        const float nrm = sqrtf(n2);
        const float av = pa * (nrm / (0.5f + n2));
        if (it < 2) {
            #pragma unroll
            for (int r = 0; r < 8; ++r) {
                float u = v[r][c][a] * av;
                #pragma unroll
                for (int m = 1; m < 16; m <<= 1) u += __shfl_xor(u, m);
                if (a == 0) logits[r][c] += u;
            }
        }
        __syncthreads();
    }
    if (a == 0) out[b * 32 + c] = n2 / (0.5f + n2);
}

// ---------------------------------------------------------------------------
extern "C" void kernel_launch(void* const* d_in, const int* in_sizes, int n_in,
                              void* d_out, int out_size, void* d_ws, size_t ws_size,
                              hipStream_t stream) {
    (void)in_sizes; (void)n_in; (void)out_size; (void)ws_size;
    const int*   tokens  = (const int*)d_in[0];
    const float* emb     = (const float*)d_in[2];
    const float* w_ih_f0 = (const float*)d_in[3];
    const float* w_hh_f0 = (const float*)d_in[4];
    const float* b_f0    = (const float*)d_in[5];
    const float* w_ih_b0 = (const float*)d_in[6];
    const float* w_hh_b0 = (const float*)d_in[7];
    const float* b_b0    = (const float*)d_in[8];
    const float* w_ih_f1 = (const float*)d_in[9];
    const float* w_hh_f1 = (const float*)d_in[10];
    const float* b_f1    = (const float*)d_in[11];
    const float* w_ih_b1 = (const float*)d_in[12];
    const float* w_hh_b1 = (const float*)d_in[13];
    const float* b_b1    = (const float*)d_in[14];
    const float* ws1     = (const float*)d_in[15];
    const float* ws2     = (const float*)d_in[16];
    const float* caps    = (const float*)d_in[17];

    float* wsf  = (float*)d_ws;
    float* Wt   = wsf;                          //  4 * 262144
    float* Z    = Wt   + 4 * 262144;            //  8192*2048
    float* x1   = Z    + 16777216;              //  8192*512
    float* outp = x1   + 4194304;               //  8192*512
    float* hbar = outp + 4194304;               //  8192*128
    float* sent = hbar + 1048576;               //  128*8*512
    float* vote = sent + 524288;                //  128*8*512
    float* hx   = vote + 524288;                //  2*2*32*1024 = 131072
    int*   flags = (int*)(hx + 131072);         //  2 * 4096 ints
    float* out  = (float*)d_out;

    // 0. zero sync flags (every launch; harness replays without re-poisoning)
    k_zero<<<dim3(32), 256, 0, stream>>>(flags, 8192);
    // 1. transpose recurrent weights
    k_transpose<<<dim3(32, 8, 4), dim3(32, 8), 0, stream>>>(w_hh_f0, w_hh_b0, w_hh_f1, w_hh_b1, Wt);
    // 2. layer-0 input projection (embedding gather fused)
    k_gemm<<<dim3(64, 16, 1), 256, 0, stream>>>(
        emb, 300, tokens, w_ih_f0, w_ih_b0, 1024, 300, b_f0, b_b0,
        Z, 2048, 300, 1, 0, 0LL, 0LL, 0LL);
    // 3. layer-0 scan (cooperative; fallback to plain launch)
    {
        const float* zc = Z; const float* wf = Wt; const float* wb = Wt + 262144;
        float* ob = x1; int bt = 0; float* hxp = hx; int* fl = flags;
        void* args[] = {(void*)&zc, (void*)&wf, (void*)&wb, (void*)&ob,
                        (void*)&bt, (void*)&hxp, (void*)&fl};
        if (hipLaunchCooperativeKernel((const void*)k_scan2, dim3(256), dim3(512),
                                       args, 0, stream) != hipSuccess)
            k_scan2<<<dim3(256), 512, 0, stream>>>(zc, wf, wb, ob, bt, hxp, fl);
    }
    // 4. layer-1 input projection
    k_gemm<<<dim3(64, 16, 1), 256, 0, stream>>>(
        x1, 512, (const int*)nullptr, w_ih_f1, w_ih_b1, 1024, 512, b_f1, b_b1,
        Z, 2048, 512, 1, 0, 0LL, 0LL, 0LL);
    // 5. layer-1 scan
    {
        const float* zc = Z; const float* wf = Wt + 2 * 262144; const float* wb = Wt + 3 * 262144;
        float* ob = outp; int bt = 1; float* hxp = hx; int* fl = flags + 4096;
        void* args[] = {(void*)&zc, (void*)&wf, (void*)&wb, (void*)&ob,
                        (void*)&bt, (void*)&hxp, (void*)&fl};
        if (hipLaunchCooperativeKernel((const void*)k_scan2, dim3(256), dim3(512),
                                       args, 0, stream) != hipSuccess)
            k_scan2<<<dim3(256), 512, 0, stream>>>(zc, wf, wb, ob, bt, hxp, fl);
    }
    // 6. hbar = tanh(outp @ ws1^T)
    k_gemm<<<dim3(64, 1, 1), 256, 0, stream>>>(
        outp, 512, (const int*)nullptr, ws1, (const float*)nullptr, 1 << 30, 512,
        (const float*)nullptr, (const float*)nullptr,
        hbar, 128, 512, 1, 1, 0LL, 0LL, 0LL);
    // 7. attention + sent
    k_attnpool<<<dim3(128), 256, 0, stream>>>(hbar, outp, ws2, sent);
    // 8. votes
    k_gemm<<<dim3(1, 4, 8), 256, 0, stream>>>(
        sent, 4096, (const int*)nullptr, caps, (const float*)nullptr, 1 << 30, 512,
        (const float*)nullptr, (const float*)nullptr,
        vote, 4096, 512, 0, 0, 512LL, 262144LL, 512LL);
    // 9. routing
    k_routing<<<dim3(128), 512, 0, stream>>>(vote, out);
}

// Round 5
// 1123.818 us; speedup vs baseline: 2.0964x; 1.4293x over previous
//
#include <hip/hip_runtime.h>

// ---------------------------------------------------------------------------
// CapsuleNetwork: embedding -> 2-layer BiLSTM -> attn pooling -> routing
// Round 4: scan sync made fence-free. All agent-scope atomics RELAXED:
//   ordering via __syncthreads()'s vmcnt(0) drain (h stores complete before
//   flag add issues); payload+flag are atomic-at-coherence-point, so no
//   acquire/release L2 invalidate/writeback per step (the R3 stall theory).
// B=128 T=64 E=300 H=256 DA=128 R=8 SC=32 AT=16
// ---------------------------------------------------------------------------

__device__ __forceinline__ float sigf(float x) { return 1.0f / (1.0f + __expf(-x)); }
__device__ __forceinline__ float tanhf_fast(float x) { return 1.0f - 2.0f / (__expf(2.0f * x) + 1.0f); }

#define DPPF(v, ctrl) __int_as_float(__builtin_amdgcn_update_dpp(0, __float_as_int(v), ctrl, 0xF, 0xF, true))

// ---------------- transpose w_hh [1024][256] -> Wt [256][1024] -------------
__global__ void k_transpose(const float* __restrict__ w0, const float* __restrict__ w1,
                            const float* __restrict__ w2, const float* __restrict__ w3,
                            float* __restrict__ wt)
{
    __shared__ float tile[32][33];
    const float* W = (blockIdx.z == 0) ? w0 : (blockIdx.z == 1) ? w1 : (blockIdx.z == 2) ? w2 : w3;
    float* Wt = wt + (size_t)blockIdx.z * 256 * 1024;
    const int j0 = blockIdx.x * 32, k0 = blockIdx.y * 32;
    const int tx = threadIdx.x, ty = threadIdx.y;  // (32,8)
    #pragma unroll
    for (int i = 0; i < 32; i += 8)
        tile[ty + i][tx] = W[(size_t)(j0 + ty + i) * 256 + (k0 + tx)];
    __syncthreads();
    #pragma unroll
    for (int i = 0; i < 32; i += 8)
        Wt[(size_t)(k0 + ty + i) * 1024 + (j0 + tx)] = tile[tx][ty + i];
}

// ---------------- zero sync flags ------------------------------------------
__global__ void k_zero(int* __restrict__ p, int n)
{
    const int i = blockIdx.x * blockDim.x + threadIdx.x;
    if (i < n) p[i] = 0;
}

// ---------------- generic fp32 GEMM (unchanged) ----------------------------
__global__ __launch_bounds__(256) void k_gemm(
    const float* __restrict__ A, int lda, const int* __restrict__ tokens,
    const float* __restrict__ W0, const float* __restrict__ W1, int nsplit, int ldw,
    const float* __restrict__ bias0, const float* __restrict__ bias1,
    float* __restrict__ C, int ldc, int K, int transb, int act_tanh,
    long long sA, long long sW, long long sC)
{
    __shared__ float As[16][128];
    __shared__ float Ws[16][128];
    A  += (size_t)blockIdx.z * (size_t)sA;
    W0 += (size_t)blockIdx.z * (size_t)sW;
    C  += (size_t)blockIdx.z * (size_t)sC;
    const int tid = threadIdx.x;
    const int m0 = blockIdx.x * 128;
    const int n0 = blockIdx.y * 128;

    const int srow = tid >> 1;
    const int kh   = (tid & 1) * 8;
    const int am = m0 + srow;
    const float* arow;
    if (tokens) {
        const int t = am >> 7, b = am & 127;
        arow = A + (size_t)tokens[b * 64 + t] * lda;
    } else {
        arow = A + (size_t)am * lda;
    }
    const int wn = n0 + srow;
    const float* wrow = (wn < nsplit) ? (W0 + (size_t)wn * ldw)
                                      : (W1 + (size_t)(wn - nsplit) * ldw);
    const int kw = tid & 15;
    const int n8 = (tid >> 4) * 8;

    const int tm = (tid & 15) * 8;
    const int tn = (tid >> 4) * 8;
    float acc[8][8] = {};

    for (int k0 = 0; k0 < K; k0 += 16) {
        if (k0 + kh + 7 < K) {
            const float4 v0 = *(const float4*)(arow + k0 + kh);
            const float4 v1 = *(const float4*)(arow + k0 + kh + 4);
            As[kh + 0][srow] = v0.x; As[kh + 1][srow] = v0.y;
            As[kh + 2][srow] = v0.z; As[kh + 3][srow] = v0.w;
            As[kh + 4][srow] = v1.x; As[kh + 5][srow] = v1.y;
            As[kh + 6][srow] = v1.z; As[kh + 7][srow] = v1.w;
        } else {
            #pragma unroll
            for (int j = 0; j < 8; ++j)
                As[kh + j][srow] = (k0 + kh + j < K) ? arow[k0 + kh + j] : 0.0f;
        }
        if (transb) {
            if (k0 + kh + 7 < K) {
                const float4 v0 = *(const float4*)(wrow + k0 + kh);
                const float4 v1 = *(const float4*)(wrow + k0 + kh + 4);
                Ws[kh + 0][srow] = v0.x; Ws[kh + 1][srow] = v0.y;
                Ws[kh + 2][srow] = v0.z; Ws[kh + 3][srow] = v0.w;
                Ws[kh + 4][srow] = v1.x; Ws[kh + 5][srow] = v1.y;
                Ws[kh + 6][srow] = v1.z; Ws[kh + 7][srow] = v1.w;
            } else {
                #pragma unroll
                for (int j = 0; j < 8; ++j)
                    Ws[kh + j][srow] = (k0 + kh + j < K) ? wrow[k0 + kh + j] : 0.0f;
            }
        } else {
            const float* src = W0 + (size_t)(k0 + kw) * ldw + n0 + n8;
            *(float4*)&Ws[kw][n8]     = *(const float4*)(src);
            *(float4*)&Ws[kw][n8 + 4] = *(const float4*)(src + 4);
        }
        __syncthreads();
        #pragma unroll
        for (int kk = 0; kk < 16; ++kk) {
            const float4 a0 = *(const float4*)&As[kk][tm];
            const float4 a1 = *(const float4*)&As[kk][tm + 4];
            const float4 b0 = *(const float4*)&Ws[kk][tn];
            const float4 b1 = *(const float4*)&Ws[kk][tn + 4];
            const float av[8] = {a0.x, a0.y, a0.z, a0.w, a1.x, a1.y, a1.z, a1.w};
            const float bv[8] = {b0.x, b0.y, b0.z, b0.w, b1.x, b1.y, b1.z, b1.w};
            #pragma unroll
            for (int i = 0; i < 8; ++i)
                #pragma unroll
                for (int j = 0; j < 8; ++j)
                    acc[i][j] += av[i] * bv[j];
        }
        __syncthreads();
    }
    const int half = (n0 >= nsplit) ? 1 : 0;
    const float* bp = half ? bias1 : bias0;
    const int nl = n0 - (half ? nsplit : 0);
    #pragma unroll
    for (int i = 0; i < 8; ++i) {
        float v[8];
        #pragma unroll
        for (int j = 0; j < 8; ++j) {
            float x = acc[i][j];
            if (bp) x += bp[nl + tn + j];
            if (act_tanh) x = tanhf_fast(x);
            v[j] = x;
        }
        float* crow = C + (size_t)(m0 + tm + i) * ldc + n0 + tn;
        *(float4*)(crow)     = make_float4(v[0], v[1], v[2], v[3]);
        *(float4*)(crow + 4) = make_float4(v[4], v[5], v[6], v[7]);
    }
}

// ---------------- full-chip BiLSTM scan ------------------------------------
// 256 blocks x 512 threads (1/CU). s = bx>>6 (dim slice), q = bx&63 (group:
// dir = q>>5, 4 batch rows). W-slice stationary in VGPRs. h in swizzled LDS.
// Exchange: RELAXED agent atomics only — ordering from __syncthreads()'s
// vmcnt(0) drain (h stores completed at coherence point before flag add
// issues; reader seeing flag==4 therefore sees all h). No acquire/release ->
// no per-step L2 invalidate/writeback.
__global__ __launch_bounds__(512, 2) void k_scan2(
    const float* __restrict__ Zin, const float* __restrict__ WtF,
    const float* __restrict__ WtB, float* __restrict__ outbuf,
    int bt_layout, float* __restrict__ hx, int* __restrict__ flags)
{
    __shared__ __align__(16) float hbuf[1024];
    __shared__ float zbuf[1024];

    const int bx  = blockIdx.x;
    const int s   = bx >> 6;
    const int q   = bx & 63;
    const int dir = q >> 5;
    const int gq  = q & 31;
    const int tid = threadIdx.x;
    const int ow  = tid >> 4;
    const int ks  = tid & 15;
    const float* __restrict__ Wt = dir ? WtB : WtF;

    // ---- preload W slice into registers (once) ----
    const int gate    = ow >> 3;
    const int colbase = gate * 256 + s * 64 + (ow & 7) * 8;
    float W[16][8];
    {
        const float* wp = Wt + (size_t)(ks * 16) * 1024 + colbase;
        #pragma unroll
        for (int i = 0; i < 16; ++i) {
            const float4 wa = *(const float4*)(wp + (size_t)i * 1024);
            const float4 wb = *(const float4*)(wp + (size_t)i * 1024 + 4);
            W[i][0] = wa.x; W[i][1] = wa.y; W[i][2] = wa.z; W[i][3] = wa.w;
            W[i][4] = wb.x; W[i][5] = wb.y; W[i][6] = wb.z; W[i][7] = wb.w;
        }
    }

    const int p2b = (tid >> 6) & 3;
    const int p2d = tid & 63;
    const int dim = s * 64 + p2d;
    const int gb  = gq * 4 + p2b;
    float c_state = 0.0f;
    const int fbase = q * 64;

    for (int tt = 0; tt < 64; ++tt) {
        const int t = dir ? (63 - tt) : tt;
        // Zin prefetch (independent of h; overlaps poll wait)
        float z0 = 0.f, z1 = 0.f, z2 = 0.f, z3 = 0.f;
        if (tid < 256) {
            const float* zr = Zin + (size_t)(t * 128 + gb) * 2048 + dir * 1024 + dim;
            z0 = zr[0]; z1 = zr[256]; z2 = zr[512]; z3 = zr[768];
        }
        if (tt > 0) {
            // ---- wait for all 4 slice-blocks to publish h(tt-1) ----
            if (tid == 0) {
                while (__hip_atomic_load(&flags[fbase + tt - 1], __ATOMIC_RELAXED,
                                         __HIP_MEMORY_SCOPE_AGENT) < 4)
                    __builtin_amdgcn_s_sleep(1);
            }
            __syncthreads();
            // ---- stage h(tt-1) into LDS (XOR-swizzled [k][4b]) ----
            {
                const float* hsrc = hx + ((((size_t)((tt - 1) & 1)) * 2 + dir) * 32 + gq) * 1024;
                #pragma unroll
                for (int j = 0; j < 2; ++j) {
                    const int idx = j * 512 + tid;
                    const int b = idx & 3, d = (idx >> 2) & 255;
                    const float v = __hip_atomic_load(&hsrc[b * 256 + d], __ATOMIC_RELAXED,
                                                      __HIP_MEMORY_SCOPE_AGENT);
                    hbuf[((d << 2) ^ (((d >> 4) & 7) << 2)) + b] = v;
                }
            }
            __syncthreads();
            // ---- phase 1: z_partial[4b][8c] over 16-k chunk (W in regs) ----
            float acc[4][8] = {};
            #pragma unroll
            for (int i = 0; i < 16; ++i) {
                const int k = ks * 16 + i;
                const float4 h4 = *(const float4*)&hbuf[(k << 2) ^ (((k >> 4) & 7) << 2)];
                const float hv[4] = {h4.x, h4.y, h4.z, h4.w};
                #pragma unroll
                for (int c = 0; c < 8; ++c)
                    #pragma unroll
                    for (int b = 0; b < 4; ++b)
                        acc[b][c] += hv[b] * W[i][c];
            }
            // ---- DPP butterfly sum over the 16 ks-lanes ----
            #pragma unroll
            for (int b = 0; b < 4; ++b)
                #pragma unroll
                for (int c = 0; c < 8; ++c) {
                    float v = acc[b][c];
                    v += DPPF(v, 0xB1);                  // xor 1
                    v += DPPF(v, 0x4E);                  // xor 2
                    v += DPPF(DPPF(v, 0x141), 0x1B);     // xor 4
                    v += DPPF(v, 0x128);                 // xor 8
                    acc[b][c] = v;
                }
            #pragma unroll
            for (int a = 0; a < 32; ++a)
                if (ks == (a >> 1))
                    zbuf[(a >> 3) * 256 + ow * 8 + (a & 7)] = acc[a >> 3][a & 7];
            __syncthreads();
        } else {
            zbuf[tid] = 0.0f;
            zbuf[512 + tid] = 0.0f;
            __syncthreads();
        }
        // ---- phase 2: gates, state update, publish h ----
        if (tid < 256) {
            const float zi = zbuf[p2b * 256 +       p2d] + z0;
            const float zf = zbuf[p2b * 256 +  64 + p2d] + z1;
            const float zg = zbuf[p2b * 256 + 128 + p2d] + z2;
            const float zo = zbuf[p2b * 256 + 192 + p2d] + z3;
            c_state = sigf(zf) * c_state + sigf(zi) * tanhf_fast(zg);
            const float h = sigf(zo) * tanhf_fast(c_state);
            const int row = bt_layout ? (gb * 64 + t) : (t * 128 + gb);
            outbuf[(size_t)row * 512 + dir * 256 + dim] = h;
            __hip_atomic_store(
                &hx[(((size_t)(tt & 1)) * 2 + dir) * 32768 + (size_t)gq * 1024 + p2b * 256 + dim],
                h, __ATOMIC_RELAXED, __HIP_MEMORY_SCOPE_AGENT);
        }
        __syncthreads();  // vmcnt(0) drain: h stores complete before flag add
        if (tid == 0)
            __hip_atomic_fetch_add(&flags[fbase + tt], 1, __ATOMIC_RELAXED,
                                   __HIP_MEMORY_SCOPE_AGENT);
    }
}

// ---------------- attention pooling (unchanged) ----------------------------
__global__ __launch_bounds__(256) void k_attnpool(
    const float* __restrict__ hbar, const float* __restrict__ outp,
    const float* __restrict__ ws2, float* __restrict__ sent)
{
    __shared__ float hb[64][132];
    __shared__ float w2[8][128];
    __shared__ float att[8][64];
    const int b = blockIdx.x, tid = threadIdx.x;
    for (int i = tid; i < 1024; i += 256) ((float*)w2)[i] = ws2[i];
    const float* hsrc = hbar + (size_t)b * 64 * 128;
    for (int i = tid; i < 2048; i += 256) {
        const int row = i >> 5, d4 = (i & 31) << 2;
        *(float4*)&hb[row][d4] = *(const float4*)(hsrc + row * 128 + d4);
    }
    __syncthreads();
    for (int p = tid; p < 512; p += 256) {
        const int r = p >> 6, t = p & 63;
        float s = 0.0f;
        #pragma unroll 8
        for (int d = 0; d < 128; d += 4) {
            const float4 x = *(const float4*)&hb[t][d];
            const float4 y = *(const float4*)&w2[r][d];
            s += x.x * y.x + x.y * y.y + x.z * y.z + x.w * y.w;
        }
        att[r][t] = s;
    }
    __syncthreads();
    const float* ob = outp + (size_t)b * 64 * 512;
    float s0[8] = {}, s1[8] = {};
    for (int t = 0; t < 64; ++t) {
        const float v0 = ob[t * 512 + tid];
        const float v1 = ob[t * 512 + 256 + tid];
        #pragma unroll
        for (int r = 0; r < 8; ++r) {
            const float a = att[r][t];
            s0[r] += a * v0; s1[r] += a * v1;
        }
    }
    #pragma unroll
    for (int r = 0; r < 8; ++r) {
        sent[((size_t)b * 8 + r) * 512 + tid]       = s0[r];
        sent[((size_t)b * 8 + r) * 512 + 256 + tid] = s1[r];
    }
}

// ---------------- dynamic routing (unchanged) ------------------------------
__global__ __launch_bounds__(512) void k_routing(
    const float* __restrict__ votes, float* __restrict__ out)
{
    __shared__ float v[8][32][16];
    __shared__ float logits[8][32];
    __shared__ float route[8][32];
    const int b = blockIdx.x, tid = threadIdx.x;
    const float* vb = votes + (size_t)b * 4096;
    for (int i = tid; i < 4096; i += 512) ((float*)v)[i] = vb[i];
    if (tid < 256) ((float*)logits)[tid] = 0.0f;
    __syncthreads();
    const int c = tid >> 4, a = tid & 15;
    float n2 = 0.0f;
    for (int it = 0; it < 3; ++it) {
        if (tid < 256) {
            const int r = tid >> 5, cc = tid & 31;
            const float l = logits[r][cc];
            float mx = l;
            #pragma unroll
            for (int m = 1; m < 32; m <<= 1) mx = fmaxf(mx, __shfl_xor(mx, m));
            const float e = __expf(l - mx);
            float sm = e;
            #pragma unroll
            for (int m = 1; m < 32; m <<= 1) sm += __shfl_xor(sm, m);
            route[r][cc] = e / sm;
        }
        __syncthreads();
        float pa = 0.0f;
        #pragma unroll
        for (int r = 0; r < 8; ++r) pa += route[r][c] * v[r][c][a];
        n2 = pa * pa;
        #pragma unroll
        for (int m = 1; m < 16; m <<= 1) n2 += __shfl_xor(n2, m);
        const float nrm = sqrtf(n2);
        const float av = pa * (nrm / (0.5f + n2));
        if (it < 2) {
            #pragma unroll
            for (int r = 0; r < 8; ++r) {
                float u = v[r][c][a] * av;
                #pragma unroll
                for (int m = 1; m < 16; m <<= 1) u += __shfl_xor(u, m);
                if (a == 0) logits[r][c] += u;
            }
        }
        __syncthreads();
    }
    if (a == 0) out[b * 32 + c] = n2 / (0.5f + n2);
}

// ---------------------------------------------------------------------------
extern "C" void kernel_launch(void* const* d_in, const int* in_sizes, int n_in,
                              void* d_out, int out_size, void* d_ws, size_t ws_size,
                              hipStream_t stream) {
    (void)in_sizes; (void)n_in; (void)out_size; (void)ws_size;
    const int*   tokens  = (const int*)d_in[0];
    const float* emb     = (const float*)d_in[2];
    const float* w_ih_f0 = (const float*)d_in[3];
    const float* w_hh_f0 = (const float*)d_in[4];
    const float* b_f0    = (const float*)d_in[5];
    const float* w_ih_b0 = (const float*)d_in[6];
    const float* w_hh_b0 = (const float*)d_in[7];
    const float* b_b0    = (const float*)d_in[8];
    const float* w_ih_f1 = (const float*)d_in[9];
    const float* w_hh_f1 = (const float*)d_in[10];
    const float* b_f1    = (const float*)d_in[11];
    const float* w_ih_b1 = (const float*)d_in[12];
    const float* w_hh_b1 = (const float*)d_in[13];
    const float* b_b1    = (const float*)d_in[14];
    const float* ws1     = (const float*)d_in[15];
    const float* ws2     = (const float*)d_in[16];
    const float* caps    = (const float*)d_in[17];

    float* wsf  = (float*)d_ws;
    float* Wt   = wsf;                          //  4 * 262144
    float* Z    = Wt   + 4 * 262144;            //  8192*2048
    float* x1   = Z    + 16777216;              //  8192*512
    float* outp = x1   + 4194304;               //  8192*512
    float* hbar = outp + 4194304;               //  8192*128
    float* sent = hbar + 1048576;               //  128*8*512
    float* vote = sent + 524288;                //  128*8*512
    float* hx   = vote + 524288;                //  2*2*32*1024 = 131072
    int*   flags = (int*)(hx + 131072);         //  2 * 4096 ints
    float* out  = (float*)d_out;

    // 0. zero sync flags (every launch; harness replays without re-poisoning)
    k_zero<<<dim3(32), 256, 0, stream>>>(flags, 8192);
    // 1. transpose recurrent weights
    k_transpose<<<dim3(32, 8, 4), dim3(32, 8), 0, stream>>>(w_hh_f0, w_hh_b0, w_hh_f1, w_hh_b1, Wt);
    // 2. layer-0 input projection (embedding gather fused)
    k_gemm<<<dim3(64, 16, 1), 256, 0, stream>>>(
        emb, 300, tokens, w_ih_f0, w_ih_b0, 1024, 300, b_f0, b_b0,
        Z, 2048, 300, 1, 0, 0LL, 0LL, 0LL);
    // 3. layer-0 scan (cooperative; fallback to plain launch)
    {
        const float* zc = Z; const float* wf = Wt; const float* wb = Wt + 262144;
        float* ob = x1; int bt = 0; float* hxp = hx; int* fl = flags;
        void* args[] = {(void*)&zc, (void*)&wf, (void*)&wb, (void*)&ob,
                        (void*)&bt, (void*)&hxp, (void*)&fl};
        if (hipLaunchCooperativeKernel((const void*)k_scan2, dim3(256), dim3(512),
                                       args, 0, stream) != hipSuccess)
            k_scan2<<<dim3(256), 512, 0, stream>>>(zc, wf, wb, ob, bt, hxp, fl);
    }
    // 4. layer-1 input projection
    k_gemm<<<dim3(64, 16, 1), 256, 0, stream>>>(
        x1, 512, (const int*)nullptr, w_ih_f1, w_ih_b1, 1024, 512, b_f1, b_b1,
        Z, 2048, 512, 1, 0, 0LL, 0LL, 0LL);
    // 5. layer-1 scan
    {
        const float* zc = Z; const float* wf = Wt + 2 * 262144; const float* wb = Wt + 3 * 262144;
        float* ob = outp; int bt = 1; float* hxp = hx; int* fl = flags + 4096;
        void* args[] = {(void*)&zc, (void*)&wf, (void*)&wb, (void*)&ob,
                        (void*)&bt, (void*)&hxp, (void*)&fl};
        if (hipLaunchCooperativeKernel((const void*)k_scan2, dim3(256), dim3(512),
                                       args, 0, stream) != hipSuccess)
            k_scan2<<<dim3(256), 512, 0, stream>>>(zc, wf, wb, ob, bt, hxp, fl);
    }
    // 6. hbar = tanh(outp @ ws1^T)
    k_gemm<<<dim3(64, 1, 1), 256, 0, stream>>>(
        outp, 512, (const int*)nullptr, ws1, (const float*)nullptr, 1 << 30, 512,
        (const float*)nullptr, (const float*)nullptr,
        hbar, 128, 512, 1, 1, 0LL, 0LL, 0LL);
    // 7. attention + sent
    k_attnpool<<<dim3(128), 256, 0, stream>>>(hbar, outp, ws2, sent);
    // 8. votes
    k_gemm<<<dim3(1, 4, 8), 256, 0, stream>>>(
        sent, 4096, (const int*)nullptr, caps, (const float*)nullptr, 1 << 30, 512,
        (const float*)nullptr, (const float*)nullptr,
        vote, 4096, 512, 0, 0, 512LL, 262144LL, 512LL);
    // 9. routing
    k_routing<<<dim3(128), 512, 0, stream>>>(vote, out);
}

// Round 6
// 1112.498 us; speedup vs baseline: 2.1177x; 1.0102x over previous
//
#include <hip/hip_runtime.h>

// ---------------------------------------------------------------------------
// CapsuleNetwork: embedding -> 2-layer BiLSTM -> attn pooling -> routing
// Round 5: scan restructured S=8 (32 h-dims/block, W=64 VGPR/thr) -> 512
// blocks = 2/CU; co-resident fwd+bwd blocks hide each other's exchange stall.
// Exchange stays RELAXED agent atomics + flag counters (R4 mechanism).
// B=128 T=64 E=300 H=256 DA=128 R=8 SC=32 AT=16
// ---------------------------------------------------------------------------

__device__ __forceinline__ float sigf(float x) { return 1.0f / (1.0f + __expf(-x)); }
__device__ __forceinline__ float tanhf_fast(float x) { return 1.0f - 2.0f / (__expf(2.0f * x) + 1.0f); }

#define DPPF(v, ctrl) __int_as_float(__builtin_amdgcn_update_dpp(0, __float_as_int(v), ctrl, 0xF, 0xF, true))

// ---------------- transpose w_hh [1024][256] -> Wt [256][1024] -------------
__global__ void k_transpose(const float* __restrict__ w0, const float* __restrict__ w1,
                            const float* __restrict__ w2, const float* __restrict__ w3,
                            float* __restrict__ wt)
{
    __shared__ float tile[32][33];
    const float* W = (blockIdx.z == 0) ? w0 : (blockIdx.z == 1) ? w1 : (blockIdx.z == 2) ? w2 : w3;
    float* Wt = wt + (size_t)blockIdx.z * 256 * 1024;
    const int j0 = blockIdx.x * 32, k0 = blockIdx.y * 32;
    const int tx = threadIdx.x, ty = threadIdx.y;  // (32,8)
    #pragma unroll
    for (int i = 0; i < 32; i += 8)
        tile[ty + i][tx] = W[(size_t)(j0 + ty + i) * 256 + (k0 + tx)];
    __syncthreads();
    #pragma unroll
    for (int i = 0; i < 32; i += 8)
        Wt[(size_t)(k0 + ty + i) * 1024 + (j0 + tx)] = tile[tx][ty + i];
}

// ---------------- zero sync flags ------------------------------------------
__global__ void k_zero(int* __restrict__ p, int n)
{
    const int i = blockIdx.x * blockDim.x + threadIdx.x;
    if (i < n) p[i] = 0;
}

// ---------------- generic fp32 GEMM (unchanged) ----------------------------
__global__ __launch_bounds__(256) void k_gemm(
    const float* __restrict__ A, int lda, const int* __restrict__ tokens,
    const float* __restrict__ W0, const float* __restrict__ W1, int nsplit, int ldw,
    const float* __restrict__ bias0, const float* __restrict__ bias1,
    float* __restrict__ C, int ldc, int K, int transb, int act_tanh,
    long long sA, long long sW, long long sC)
{
    __shared__ float As[16][128];
    __shared__ float Ws[16][128];
    A  += (size_t)blockIdx.z * (size_t)sA;
    W0 += (size_t)blockIdx.z * (size_t)sW;
    C  += (size_t)blockIdx.z * (size_t)sC;
    const int tid = threadIdx.x;
    const int m0 = blockIdx.x * 128;
    const int n0 = blockIdx.y * 128;

    const int srow = tid >> 1;
    const int kh   = (tid & 1) * 8;
    const int am = m0 + srow;
    const float* arow;
    if (tokens) {
        const int t = am >> 7, b = am & 127;
        arow = A + (size_t)tokens[b * 64 + t] * lda;
    } else {
        arow = A + (size_t)am * lda;
    }
    const int wn = n0 + srow;
    const float* wrow = (wn < nsplit) ? (W0 + (size_t)wn * ldw)
                                      : (W1 + (size_t)(wn - nsplit) * ldw);
    const int kw = tid & 15;
    const int n8 = (tid >> 4) * 8;

    const int tm = (tid & 15) * 8;
    const int tn = (tid >> 4) * 8;
    float acc[8][8] = {};

    for (int k0 = 0; k0 < K; k0 += 16) {
        if (k0 + kh + 7 < K) {
            const float4 v0 = *(const float4*)(arow + k0 + kh);
            const float4 v1 = *(const float4*)(arow + k0 + kh + 4);
            As[kh + 0][srow] = v0.x; As[kh + 1][srow] = v0.y;
            As[kh + 2][srow] = v0.z; As[kh + 3][srow] = v0.w;
            As[kh + 4][srow] = v1.x; As[kh + 5][srow] = v1.y;
            As[kh + 6][srow] = v1.z; As[kh + 7][srow] = v1.w;
        } else {
            #pragma unroll
            for (int j = 0; j < 8; ++j)
                As[kh + j][srow] = (k0 + kh + j < K) ? arow[k0 + kh + j] : 0.0f;
        }
        if (transb) {
            if (k0 + kh + 7 < K) {
                const float4 v0 = *(const float4*)(wrow + k0 + kh);
                const float4 v1 = *(const float4*)(wrow + k0 + kh + 4);
                Ws[kh + 0][srow] = v0.x; Ws[kh + 1][srow] = v0.y;
                Ws[kh + 2][srow] = v0.z; Ws[kh + 3][srow] = v0.w;
                Ws[kh + 4][srow] = v1.x; Ws[kh + 5][srow] = v1.y;
                Ws[kh + 6][srow] = v1.z; Ws[kh + 7][srow] = v1.w;
            } else {
                #pragma unroll
                for (int j = 0; j < 8; ++j)
                    Ws[kh + j][srow] = (k0 + kh + j < K) ? wrow[k0 + kh + j] : 0.0f;
            }
        } else {
            const float* src = W0 + (size_t)(k0 + kw) * ldw + n0 + n8;
            *(float4*)&Ws[kw][n8]     = *(const float4*)(src);
            *(float4*)&Ws[kw][n8 + 4] = *(const float4*)(src + 4);
        }
        __syncthreads();
        #pragma unroll
        for (int kk = 0; kk < 16; ++kk) {
            const float4 a0 = *(const float4*)&As[kk][tm];
            const float4 a1 = *(const float4*)&As[kk][tm + 4];
            const float4 b0 = *(const float4*)&Ws[kk][tn];
            const float4 b1 = *(const float4*)&Ws[kk][tn + 4];
            const float av[8] = {a0.x, a0.y, a0.z, a0.w, a1.x, a1.y, a1.z, a1.w};
            const float bv[8] = {b0.x, b0.y, b0.z, b0.w, b1.x, b1.y, b1.z, b1.w};
            #pragma unroll
            for (int i = 0; i < 8; ++i)
                #pragma unroll
                for (int j = 0; j < 8; ++j)
                    acc[i][j] += av[i] * bv[j];
        }
        __syncthreads();
    }
    const int half = (n0 >= nsplit) ? 1 : 0;
    const float* bp = half ? bias1 : bias0;
    const int nl = n0 - (half ? nsplit : 0);
    #pragma unroll
    for (int i = 0; i < 8; ++i) {
        float v[8];
        #pragma unroll
        for (int j = 0; j < 8; ++j) {
            float x = acc[i][j];
            if (bp) x += bp[nl + tn + j];
            if (act_tanh) x = tanhf_fast(x);
            v[j] = x;
        }
        float* crow = C + (size_t)(m0 + tm + i) * ldc + n0 + tn;
        *(float4*)(crow)     = make_float4(v[0], v[1], v[2], v[3]);
        *(float4*)(crow + 4) = make_float4(v[4], v[5], v[6], v[7]);
    }
}

// ---------------- full-chip BiLSTM scan, S=8 / 2 blocks per CU -------------
// 512 blocks x 512 thr. bx = dir*256 + s*32 + q:
//   dir = bx>>8; s = (bx&255)>>5 (col slice: 32 cols/gate, h dims s*32..+31);
//   q = bx&31 (4 batch rows). Group = 8 slice-blocks of same (dir,q);
//   members share bx%8 = q%8 (same-XCD heuristic) and live in one 256-half
//   (fallback two-launch path stays self-contained).
// Thread: cg = tid>>4 (4 cols), ks = tid&15 (16 k). W[16][4] = 64 VGPR.
// __launch_bounds__(512,4) -> 16 waves/CU -> 2 blocks (fwd+bwd) per CU so
// one block's exchange stall overlaps the other's FMA.
__global__ __launch_bounds__(512, 4) void k_scan3(
    const float* __restrict__ Zin, const float* __restrict__ WtF,
    const float* __restrict__ WtB, float* __restrict__ outbuf,
    int bt_layout, float* __restrict__ hx, int* __restrict__ flags, int bx_base)
{
    __shared__ __align__(16) float hbuf[1024];   // h, XOR-swizzled [k][4b]
    __shared__ float zbuf[512];                  // [4b][128 local cols]

    const int bx  = blockIdx.x + bx_base;
    const int dir = bx >> 8;
    const int s   = (bx & 255) >> 5;
    const int q   = bx & 31;
    const int tid = threadIdx.x;
    const int cg  = tid >> 4;
    const int ks  = tid & 15;
    const float* __restrict__ Wt = dir ? WtB : WtF;

    // ---- preload W slice (once): 4 cols x 16 k per thread ----
    const int gate    = cg >> 3;
    const int colbase = gate * 256 + s * 32 + (cg & 7) * 4;
    float W[16][4];
    {
        const float* wp = Wt + (size_t)(ks * 16) * 1024 + colbase;
        #pragma unroll
        for (int i = 0; i < 16; ++i) {
            const float4 wa = *(const float4*)(wp + (size_t)i * 1024);
            W[i][0] = wa.x; W[i][1] = wa.y; W[i][2] = wa.z; W[i][3] = wa.w;
        }
    }

    const int pb  = tid >> 5;          // batch 0..3   (phase2, tid<128)
    const int pd  = tid & 31;          // local dim
    const int dim = s * 32 + pd;
    const int gb  = q * 4 + pb;
    float c_state = 0.0f;
    const int fbase = (dir * 32 + q) * 64;

    for (int tt = 0; tt < 64; ++tt) {
        const int t = dir ? (63 - tt) : tt;
        // Zin prefetch (independent of h; overlaps poll wait)
        float z0 = 0.f, z1 = 0.f, z2 = 0.f, z3 = 0.f;
        if (tid < 128) {
            const float* zr = Zin + (size_t)(t * 128 + gb) * 2048 + dir * 1024 + dim;
            z0 = zr[0]; z1 = zr[256]; z2 = zr[512]; z3 = zr[768];
        }
        if (tt > 0) {
            // ---- wait for all 8 slice-blocks to publish h(tt-1) ----
            if (tid == 0) {
                while (__hip_atomic_load(&flags[fbase + tt - 1], __ATOMIC_RELAXED,
                                         __HIP_MEMORY_SCOPE_AGENT) < 8)
                    __builtin_amdgcn_s_sleep(1);
            }
            __syncthreads();
            // ---- stage h(tt-1) into LDS (XOR-swizzled [k][4b]) ----
            {
                const float* hsrc = hx + ((((size_t)((tt - 1) & 1)) * 2 + dir) * 32 + q) * 1024;
                #pragma unroll
                for (int j = 0; j < 2; ++j) {
                    const int idx = j * 512 + tid;
                    const int b = idx & 3, d = (idx >> 2) & 255;
                    const float v = __hip_atomic_load(&hsrc[b * 256 + d], __ATOMIC_RELAXED,
                                                      __HIP_MEMORY_SCOPE_AGENT);
                    hbuf[((d << 2) ^ (((d >> 4) & 7) << 2)) + b] = v;
                }
            }
            __syncthreads();
            // ---- phase 1: z_partial[4b][4c] over 16-k chunk (W in regs) ----
            float acc[4][4] = {};
            #pragma unroll
            for (int i = 0; i < 16; ++i) {
                const int k = ks * 16 + i;
                const float4 h4 = *(const float4*)&hbuf[(k << 2) ^ (((k >> 4) & 7) << 2)];
                const float hv[4] = {h4.x, h4.y, h4.z, h4.w};
                #pragma unroll
                for (int c = 0; c < 4; ++c)
                    #pragma unroll
                    for (int b = 0; b < 4; ++b)
                        acc[b][c] += hv[b] * W[i][c];
            }
            // ---- DPP butterfly all-reduce over the 16 ks-lanes ----
            #pragma unroll
            for (int b = 0; b < 4; ++b)
                #pragma unroll
                for (int c = 0; c < 4; ++c) {
                    float v = acc[b][c];
                    v += DPPF(v, 0xB1);                  // xor 1
                    v += DPPF(v, 0x4E);                  // xor 2
                    v += DPPF(DPPF(v, 0x141), 0x1B);     // xor 4
                    v += DPPF(v, 0x128);                 // xor 8
                    acc[b][c] = v;
                }
            // lane ks writes value (b,c) = (ks>>2, ks&3) (static idx, predicated)
            #pragma unroll
            for (int a = 0; a < 16; ++a)
                if (ks == a)
                    zbuf[(a >> 2) * 128 + gate * 32 + (cg & 7) * 4 + (a & 3)] = acc[a >> 2][a & 3];
            __syncthreads();
        } else {
            zbuf[tid & 511] = 0.0f;
            __syncthreads();
        }
        // ---- phase 2: gates, state update, publish h ----
        if (tid < 128) {
            const float zi = zbuf[pb * 128 +      pd] + z0;
            const float zf = zbuf[pb * 128 + 32 + pd] + z1;
            const float zg = zbuf[pb * 128 + 64 + pd] + z2;
            const float zo = zbuf[pb * 128 + 96 + pd] + z3;
            c_state = sigf(zf) * c_state + sigf(zi) * tanhf_fast(zg);
            const float h = sigf(zo) * tanhf_fast(c_state);
            const int row = bt_layout ? (gb * 64 + t) : (t * 128 + gb);
            outbuf[(size_t)row * 512 + dir * 256 + dim] = h;
            __hip_atomic_store(
                &hx[(((size_t)(tt & 1)) * 2 + dir) * 32768 + (size_t)q * 1024 + pb * 256 + dim],
                h, __ATOMIC_RELAXED, __HIP_MEMORY_SCOPE_AGENT);
        }
        __syncthreads();  // vmcnt(0) drain: h stores complete before flag add
        if (tid == 0)
            __hip_atomic_fetch_add(&flags[fbase + tt], 1, __ATOMIC_RELAXED,
                                   __HIP_MEMORY_SCOPE_AGENT);
    }
}

// ---------------- attention pooling (unchanged) ----------------------------
__global__ __launch_bounds__(256) void k_attnpool(
    const float* __restrict__ hbar, const float* __restrict__ outp,
    const float* __restrict__ ws2, float* __restrict__ sent)
{
    __shared__ float hb[64][132];
    __shared__ float w2[8][128];
    __shared__ float att[8][64];
    const int b = blockIdx.x, tid = threadIdx.x;
    for (int i = tid; i < 1024; i += 256) ((float*)w2)[i] = ws2[i];
    const float* hsrc = hbar + (size_t)b * 64 * 128;
    for (int i = tid; i < 2048; i += 256) {
        const int row = i >> 5, d4 = (i & 31) << 2;
        *(float4*)&hb[row][d4] = *(const float4*)(hsrc + row * 128 + d4);
    }
    __syncthreads();
    for (int p = tid; p < 512; p += 256) {
        const int r = p >> 6, t = p & 63;
        float s = 0.0f;
        #pragma unroll 8
        for (int d = 0; d < 128; d += 4) {
            const float4 x = *(const float4*)&hb[t][d];
            const float4 y = *(const float4*)&w2[r][d];
            s += x.x * y.x + x.y * y.y + x.z * y.z + x.w * y.w;
        }
        att[r][t] = s;
    }
    __syncthreads();
    const float* ob = outp + (size_t)b * 64 * 512;
    float s0[8] = {}, s1[8] = {};
    for (int t = 0; t < 64; ++t) {
        const float v0 = ob[t * 512 + tid];
        const float v1 = ob[t * 512 + 256 + tid];
        #pragma unroll
        for (int r = 0; r < 8; ++r) {
            const float a = att[r][t];
            s0[r] += a * v0; s1[r] += a * v1;
        }
    }
    #pragma unroll
    for (int r = 0; r < 8; ++r) {
        sent[((size_t)b * 8 + r) * 512 + tid]       = s0[r];
        sent[((size_t)b * 8 + r) * 512 + 256 + tid] = s1[r];
    }
}

// ---------------- dynamic routing (unchanged) ------------------------------
__global__ __launch_bounds__(512) void k_routing(
    const float* __restrict__ votes, float* __restrict__ out)
{
    __shared__ float v[8][32][16];
    __shared__ float logits[8][32];
    __shared__ float route[8][32];
    const int b = blockIdx.x, tid = threadIdx.x;
    const float* vb = votes + (size_t)b * 4096;
    for (int i = tid; i < 4096; i += 512) ((float*)v)[i] = vb[i];
    if (tid < 256) ((float*)logits)[tid] = 0.0f;
    __syncthreads();
    const int c = tid >> 4, a = tid & 15;
    float n2 = 0.0f;
    for (int it = 0; it < 3; ++it) {
        if (tid < 256) {
            const int r = tid >> 5, cc = tid & 31;
            const float l = logits[r][cc];
            float mx = l;
            #pragma unroll
            for (int m = 1; m < 32; m <<= 1) mx = fmaxf(mx, __shfl_xor(mx, m));
            const float e = __expf(l - mx);
            float sm = e;
            #pragma unroll
            for (int m = 1; m < 32; m <<= 1) sm += __shfl_xor(sm, m);
            route[r][cc] = e / sm;
        }
        __syncthreads();
        float pa = 0.0f;
        #pragma unroll
        for (int r = 0; r < 8; ++r) pa += route[r][c] * v[r][c][a];
        n2 = pa * pa;
        #pragma unroll
        for (int m = 1; m < 16; m <<= 1) n2 += __shfl_xor(n2, m);
        const float nrm = sqrtf(n2);
        const float av = pa * (nrm / (0.5f + n2));
        if (it < 2) {
            #pragma unroll
            for (int r = 0; r < 8; ++r) {
                float u = v[r][c][a] * av;
                #pragma unroll
                for (int m = 1; m < 16; m <<= 1) u += __shfl_xor(u, m);
                if (a == 0) logits[r][c] += u;
            }
        }
        __syncthreads();
    }
    if (a == 0) out[b * 32 + c] = n2 / (0.5f + n2);
}

// ---------------------------------------------------------------------------
static void launch_scan(const float* Z, const float* wf, const float* wb,
                        float* ob, int bt, float* hx, int* fl, hipStream_t stream)
{
    int base0 = 0;
    void* args[] = {(void*)&Z, (void*)&wf, (void*)&wb, (void*)&ob,
                    (void*)&bt, (void*)&hx, (void*)&fl, (void*)&base0};
    if (hipLaunchCooperativeKernel((const void*)k_scan3, dim3(512), dim3(512),
                                   args, 0, stream) != hipSuccess) {
        // Fallback: two self-contained 256-block launches (dir0 then dir1).
        k_scan3<<<dim3(256), 512, 0, stream>>>(Z, wf, wb, ob, bt, hx, fl, 0);
        k_scan3<<<dim3(256), 512, 0, stream>>>(Z, wf, wb, ob, bt, hx, fl, 256);
    }
}

extern "C" void kernel_launch(void* const* d_in, const int* in_sizes, int n_in,
                              void* d_out, int out_size, void* d_ws, size_t ws_size,
                              hipStream_t stream) {
    (void)in_sizes; (void)n_in; (void)out_size; (void)ws_size;
    const int*   tokens  = (const int*)d_in[0];
    const float* emb     = (const float*)d_in[2];
    const float* w_ih_f0 = (const float*)d_in[3];
    const float* w_hh_f0 = (const float*)d_in[4];
    const float* b_f0    = (const float*)d_in[5];
    const float* w_ih_b0 = (const float*)d_in[6];
    const float* w_hh_b0 = (const float*)d_in[7];
    const float* b_b0    = (const float*)d_in[8];
    const float* w_ih_f1 = (const float*)d_in[9];
    const float* w_hh_f1 = (const float*)d_in[10];
    const float* b_f1    = (const float*)d_in[11];
    const float* w_ih_b1 = (const float*)d_in[12];
    const float* w_hh_b1 = (const float*)d_in[13];
    const float* b_b1    = (const float*)d_in[14];
    const float* ws1     = (const float*)d_in[15];
    const float* ws2     = (const float*)d_in[16];
    const float* caps    = (const float*)d_in[17];

    float* wsf  = (float*)d_ws;
    float* Wt   = wsf;                          //  4 * 262144
    float* Z    = Wt   + 4 * 262144;            //  8192*2048
    float* x1   = Z    + 16777216;              //  8192*512
    float* outp = x1   + 4194304;               //  8192*512
    float* hbar = outp + 4194304;               //  8192*128
    float* sent = hbar + 1048576;               //  128*8*512
    float* vote = sent + 524288;                //  128*8*512
    float* hx   = vote + 524288;                //  2*2*32*1024 = 131072
    int*   flags = (int*)(hx + 131072);         //  2 * 4096 ints
    float* out  = (float*)d_out;

    // 0. zero sync flags (every launch; replays don't re-poison)
    k_zero<<<dim3(32), 256, 0, stream>>>(flags, 8192);
    // 1. transpose recurrent weights
    k_transpose<<<dim3(32, 8, 4), dim3(32, 8), 0, stream>>>(w_hh_f0, w_hh_b0, w_hh_f1, w_hh_b1, Wt);
    // 2. layer-0 input projection (embedding gather fused)
    k_gemm<<<dim3(64, 16, 1), 256, 0, stream>>>(
        emb, 300, tokens, w_ih_f0, w_ih_b0, 1024, 300, b_f0, b_b0,
        Z, 2048, 300, 1, 0, 0LL, 0LL, 0LL);
    // 3. layer-0 scan -> x1 [t*128+b][512]
    launch_scan(Z, Wt, Wt + 262144, x1, 0, hx, flags, stream);
    // 4. layer-1 input projection
    k_gemm<<<dim3(64, 16, 1), 256, 0, stream>>>(
        x1, 512, (const int*)nullptr, w_ih_f1, w_ih_b1, 1024, 512, b_f1, b_b1,
        Z, 2048, 512, 1, 0, 0LL, 0LL, 0LL);
    // 5. layer-1 scan -> outp [b*64+t][512]
    launch_scan(Z, Wt + 2 * 262144, Wt + 3 * 262144, outp, 1, hx, flags + 4096, stream);
    // 6. hbar = tanh(outp @ ws1^T)
    k_gemm<<<dim3(64, 1, 1), 256, 0, stream>>>(
        outp, 512, (const int*)nullptr, ws1, (const float*)nullptr, 1 << 30, 512,
        (const float*)nullptr, (const float*)nullptr,
        hbar, 128, 512, 1, 1, 0LL, 0LL, 0LL);
    // 7. attention + sent
    k_attnpool<<<dim3(128), 256, 0, stream>>>(hbar, outp, ws2, sent);
    // 8. votes
    k_gemm<<<dim3(1, 4, 8), 256, 0, stream>>>(
        sent, 4096, (const int*)nullptr, caps, (const float*)nullptr, 1 << 30, 512,
        (const float*)nullptr, (const float*)nullptr,
        vote, 4096, 512, 0, 0, 512LL, 262144LL, 512LL);
    // 9. routing
    k_routing<<<dim3(128), 512, 0, stream>>>(vote, out);
}

// Round 7
// 1094.693 us; speedup vs baseline: 2.1522x; 1.0163x over previous
//
#include <hip/hip_runtime.h>

// ---------------------------------------------------------------------------
// CapsuleNetwork: embedding -> 2-layer BiLSTM -> attn pooling -> routing
// Round 6: (1) GEMM rebuilt: BK=32, conflict-free row-quad microtile,
//              register double-buffered staging (prefetch under FMA).
//          (2) Scan: K_split 16->8 (reduce ops 144->56, zbuf writes 16->8).
// Exchange stays RELAXED agent atomics + flag counters (R4 mechanism).
// B=128 T=64 E=300 H=256 DA=128 R=8 SC=32 AT=16
// ---------------------------------------------------------------------------

__device__ __forceinline__ float sigf(float x) { return 1.0f / (1.0f + __expf(-x)); }
__device__ __forceinline__ float tanhf_fast(float x) { return 1.0f - 2.0f / (__expf(2.0f * x) + 1.0f); }

#define DPPF(v, ctrl) __int_as_float(__builtin_amdgcn_update_dpp(0, __float_as_int(v), ctrl, 0xF, 0xF, true))

// ---------------- transpose w_hh [1024][256] -> Wt [256][1024] -------------
__global__ void k_transpose(const float* __restrict__ w0, const float* __restrict__ w1,
                            const float* __restrict__ w2, const float* __restrict__ w3,
                            float* __restrict__ wt)
{
    __shared__ float tile[32][33];
    const float* W = (blockIdx.z == 0) ? w0 : (blockIdx.z == 1) ? w1 : (blockIdx.z == 2) ? w2 : w3;
    float* Wt = wt + (size_t)blockIdx.z * 256 * 1024;
    const int j0 = blockIdx.x * 32, k0 = blockIdx.y * 32;
    const int tx = threadIdx.x, ty = threadIdx.y;  // (32,8)
    #pragma unroll
    for (int i = 0; i < 32; i += 8)
        tile[ty + i][tx] = W[(size_t)(j0 + ty + i) * 256 + (k0 + tx)];
    __syncthreads();
    #pragma unroll
    for (int i = 0; i < 32; i += 8)
        Wt[(size_t)(k0 + ty + i) * 1024 + (j0 + tx)] = tile[tx][ty + i];
}

// ---------------- zero sync flags ------------------------------------------
__global__ void k_zero(int* __restrict__ p, int n)
{
    const int i = blockIdx.x * blockDim.x + threadIdx.x;
    if (i < n) p[i] = 0;
}

// ---------------- fp32 GEMM, BK=32, reg-double-buffered --------------------
// C[m,n] = act( sum_k A[m,k]*W[n,k] + bias[n] )   (transb=1)
// C[m,n] = act( sum_k A[m,k]*W[k,n] + bias[n] )   (transb=0)
// Tile 128x128, 256 thr. Microtile: rows {tm4..+3, tm4+64..+67},
// cols {tn4..+3, tn4+64..+67} -> lane-stride-4 LDS reads (2-way, free).
__global__ __launch_bounds__(256) void k_gemm(
    const float* __restrict__ A, int lda, const int* __restrict__ tokens,
    const float* __restrict__ W0, const float* __restrict__ W1, int nsplit, int ldw,
    const float* __restrict__ bias0, const float* __restrict__ bias1,
    float* __restrict__ C, int ldc, int K, int transb, int act_tanh,
    long long sA, long long sW, long long sC)
{
    __shared__ float As[32][128];
    __shared__ float Ws[32][128];
    A  += (size_t)blockIdx.z * (size_t)sA;
    W0 += (size_t)blockIdx.z * (size_t)sW;
    C  += (size_t)blockIdx.z * (size_t)sC;
    const int tid = threadIdx.x;
    const int m0 = blockIdx.x * 128;
    const int n0 = blockIdx.y * 128;

    // A staging (row-major A): srow = tid>>1, kh = (tid&1)*16, 4x float4
    const int srow = tid >> 1;
    const int kh   = (tid & 1) * 16;
    const int am = m0 + srow;
    const float* arow;
    if (tokens) {
        const int t = am >> 7, b = am & 127;
        arow = A + (size_t)tokens[b * 64 + t] * lda;
    } else {
        arow = A + (size_t)am * lda;
    }
    // W staging transb=1: same pattern on W rows
    const int wn = n0 + srow;
    const float* wrow = (wn < nsplit) ? (W0 + (size_t)wn * ldw)
                                      : (W1 + (size_t)(wn - nsplit) * ldw);
    // W staging transb=0: kw = tid>>3 (32 k-rows), n8 = (tid&7)*16
    const int kw = tid >> 3;
    const int n8 = (tid & 7) * 16;

    const int tm4 = (tid & 15) * 4;
    const int tn4 = (tid >> 4) * 4;
    float acc[8][8] = {};
    float4 ra[4], rw[4];

    const int nt = (K + 31) / 32;

    // ---- prefetch tile 0 into registers ----
    #pragma unroll
    for (int j = 0; j < 4; ++j) {
        const int k = kh + j * 4;
        if (k + 3 < K) ra[j] = *(const float4*)(arow + k);
        else {
            float t0 = (k + 0 < K) ? arow[k + 0] : 0.f;
            float t1 = (k + 1 < K) ? arow[k + 1] : 0.f;
            float t2 = (k + 2 < K) ? arow[k + 2] : 0.f;
            float t3 = (k + 3 < K) ? arow[k + 3] : 0.f;
            ra[j] = make_float4(t0, t1, t2, t3);
        }
    }
    if (transb) {
        #pragma unroll
        for (int j = 0; j < 4; ++j) {
            const int k = kh + j * 4;
            if (k + 3 < K) rw[j] = *(const float4*)(wrow + k);
            else {
                float t0 = (k + 0 < K) ? wrow[k + 0] : 0.f;
                float t1 = (k + 1 < K) ? wrow[k + 1] : 0.f;
                float t2 = (k + 2 < K) ? wrow[k + 2] : 0.f;
                float t3 = (k + 3 < K) ? wrow[k + 3] : 0.f;
                rw[j] = make_float4(t0, t1, t2, t3);
            }
        }
    } else {
        const float* src = (kw < K) ? (W0 + (size_t)kw * ldw + n0 + n8) : W0;
        #pragma unroll
        for (int j = 0; j < 4; ++j)
            rw[j] = (kw < K) ? *(const float4*)(src + j * 4) : make_float4(0, 0, 0, 0);
    }

    for (int tile = 0; tile < nt; ++tile) {
        // ---- write prefetched regs to LDS ----
        #pragma unroll
        for (int j = 0; j < 4; ++j) {
            As[kh + j * 4 + 0][srow] = ra[j].x;
            As[kh + j * 4 + 1][srow] = ra[j].y;
            As[kh + j * 4 + 2][srow] = ra[j].z;
            As[kh + j * 4 + 3][srow] = ra[j].w;
        }
        if (transb) {
            #pragma unroll
            for (int j = 0; j < 4; ++j) {
                Ws[kh + j * 4 + 0][srow] = rw[j].x;
                Ws[kh + j * 4 + 1][srow] = rw[j].y;
                Ws[kh + j * 4 + 2][srow] = rw[j].z;
                Ws[kh + j * 4 + 3][srow] = rw[j].w;
            }
        } else {
            #pragma unroll
            for (int j = 0; j < 4; ++j)
                *(float4*)&Ws[kw][n8 + j * 4] = rw[j];
        }
        __syncthreads();
        // ---- prefetch next tile (hidden under the FMA loop below) ----
        if (tile + 1 < nt) {
            const int kb = (tile + 1) * 32;
            #pragma unroll
            for (int j = 0; j < 4; ++j) {
                const int k = kb + kh + j * 4;
                if (k + 3 < K) ra[j] = *(const float4*)(arow + k);
                else {
                    float t0 = (k + 0 < K) ? arow[k + 0] : 0.f;
                    float t1 = (k + 1 < K) ? arow[k + 1] : 0.f;
                    float t2 = (k + 2 < K) ? arow[k + 2] : 0.f;
                    float t3 = (k + 3 < K) ? arow[k + 3] : 0.f;
                    ra[j] = make_float4(t0, t1, t2, t3);
                }
            }
            if (transb) {
                #pragma unroll
                for (int j = 0; j < 4; ++j) {
                    const int k = kb + kh + j * 4;
                    if (k + 3 < K) rw[j] = *(const float4*)(wrow + k);
                    else {
                        float t0 = (k + 0 < K) ? wrow[k + 0] : 0.f;
                        float t1 = (k + 1 < K) ? wrow[k + 1] : 0.f;
                        float t2 = (k + 2 < K) ? wrow[k + 2] : 0.f;
                        float t3 = (k + 3 < K) ? wrow[k + 3] : 0.f;
                        rw[j] = make_float4(t0, t1, t2, t3);
                    }
                }
            } else {
                const int k = kb + kw;
                const float* src = (k < K) ? (W0 + (size_t)k * ldw + n0 + n8) : W0;
                #pragma unroll
                for (int j = 0; j < 4; ++j)
                    rw[j] = (k < K) ? *(const float4*)(src + j * 4) : make_float4(0, 0, 0, 0);
            }
        }
        // ---- compute 32 kk ----
        #pragma unroll 8
        for (int kk = 0; kk < 32; ++kk) {
            const float4 a0 = *(const float4*)&As[kk][tm4];
            const float4 a1 = *(const float4*)&As[kk][tm4 + 64];
            const float4 b0 = *(const float4*)&Ws[kk][tn4];
            const float4 b1 = *(const float4*)&Ws[kk][tn4 + 64];
            const float av[8] = {a0.x, a0.y, a0.z, a0.w, a1.x, a1.y, a1.z, a1.w};
            const float bv[8] = {b0.x, b0.y, b0.z, b0.w, b1.x, b1.y, b1.z, b1.w};
            #pragma unroll
            for (int i = 0; i < 8; ++i)
                #pragma unroll
                for (int j = 0; j < 8; ++j)
                    acc[i][j] += av[i] * bv[j];
        }
        __syncthreads();
    }
    // ---- epilogue: rows tm4+(i>>2)*64+(i&3), cols tn4+(j>>2)*64+(j&3) ----
    const int half = (n0 >= nsplit) ? 1 : 0;
    const float* bp = half ? bias1 : bias0;
    const int nl = n0 - (half ? nsplit : 0);
    #pragma unroll
    for (int i = 0; i < 8; ++i) {
        const int row = m0 + tm4 + (i >> 2) * 64 + (i & 3);
        #pragma unroll
        for (int jh = 0; jh < 2; ++jh) {
            float v[4];
            #pragma unroll
            for (int j = 0; j < 4; ++j) {
                float x = acc[i][jh * 4 + j];
                if (bp) x += bp[nl + tn4 + jh * 64 + j];
                if (act_tanh) x = tanhf_fast(x);
                v[j] = x;
            }
            *(float4*)(C + (size_t)row * ldc + n0 + tn4 + jh * 64) =
                make_float4(v[0], v[1], v[2], v[3]);
        }
    }
}

// ---------------- full-chip BiLSTM scan, S=8, K_split=8 --------------------
// 512 blocks x 512 thr (2/CU). bx = dir*256 + s*32 + q.
// Thread: cg = tid>>3 (2 cols), ks = tid&7 (32 k). W[32][2] = 64 VGPR.
// Reduce: 3-stage DPP butterfly over 8 lanes; 8 predicated zbuf writes.
__global__ __launch_bounds__(512, 4) void k_scan4(
    const float* __restrict__ Zin, const float* __restrict__ WtF,
    const float* __restrict__ WtB, float* __restrict__ outbuf,
    int bt_layout, float* __restrict__ hx, int* __restrict__ flags, int bx_base)
{
    __shared__ __align__(16) float hbuf[1024];   // h, XOR-swizzled [k][4b]
    __shared__ float zbuf[512];                  // [4b][128 local cols]

    const int bx  = blockIdx.x + bx_base;
    const int dir = bx >> 8;
    const int s   = (bx & 255) >> 5;
    const int q   = bx & 31;
    const int tid = threadIdx.x;
    const int cg  = tid >> 3;          // 0..63 col group (2 cols)
    const int ks  = tid & 7;           // 0..7  k chunk (32 k)
    const float* __restrict__ Wt = dir ? WtB : WtF;

    // ---- preload W slice (once): 2 cols x 32 k per thread ----
    const int gate    = cg >> 4;                    // 0..3
    const int wg      = cg & 15;                    // 0..15
    const int colbase = gate * 256 + s * 32 + wg * 2;
    float W[32][2];
    {
        const float* wp = Wt + (size_t)(ks * 32) * 1024 + colbase;
        #pragma unroll
        for (int i = 0; i < 32; ++i) {
            const float2 w2 = *(const float2*)(wp + (size_t)i * 1024);
            W[i][0] = w2.x; W[i][1] = w2.y;
        }
    }

    const int pb  = tid >> 5;          // batch 0..3   (phase2, tid<128)
    const int pd  = tid & 31;          // local dim
    const int dim = s * 32 + pd;
    const int gb  = q * 4 + pb;
    float c_state = 0.0f;
    const int fbase = (dir * 32 + q) * 64;

    for (int tt = 0; tt < 64; ++tt) {
        const int t = dir ? (63 - tt) : tt;
        // Zin prefetch (independent of h; overlaps poll wait)
        float z0 = 0.f, z1 = 0.f, z2 = 0.f, z3 = 0.f;
        if (tid < 128) {
            const float* zr = Zin + (size_t)(t * 128 + gb) * 2048 + dir * 1024 + dim;
            z0 = zr[0]; z1 = zr[256]; z2 = zr[512]; z3 = zr[768];
        }
        if (tt > 0) {
            // ---- wait for all 8 slice-blocks to publish h(tt-1) ----
            if (tid == 0) {
                while (__hip_atomic_load(&flags[fbase + tt - 1], __ATOMIC_RELAXED,
                                         __HIP_MEMORY_SCOPE_AGENT) < 8)
                    __builtin_amdgcn_s_sleep(1);
            }
            __syncthreads();
            // ---- stage h(tt-1) into LDS (XOR-swizzled [k][4b]) ----
            {
                const float* hsrc = hx + ((((size_t)((tt - 1) & 1)) * 2 + dir) * 32 + q) * 1024;
                #pragma unroll
                for (int j = 0; j < 2; ++j) {
                    const int idx = j * 512 + tid;
                    const int b = idx & 3, d = (idx >> 2) & 255;
                    const float v = __hip_atomic_load(&hsrc[b * 256 + d], __ATOMIC_RELAXED,
                                                      __HIP_MEMORY_SCOPE_AGENT);
                    hbuf[((d << 2) ^ (((d >> 4) & 7) << 2)) + b] = v;
                }
            }
            __syncthreads();
            // ---- phase 1: z_partial[4b][2c] over 32-k chunk (W in regs) ----
            float acc[4][2] = {};
            #pragma unroll
            for (int i = 0; i < 32; ++i) {
                const int k = (ks << 5) + i;
                const float4 h4 = *(const float4*)&hbuf[(k << 2) ^ (((k >> 4) & 7) << 2)];
                acc[0][0] += h4.x * W[i][0]; acc[0][1] += h4.x * W[i][1];
                acc[1][0] += h4.y * W[i][0]; acc[1][1] += h4.y * W[i][1];
                acc[2][0] += h4.z * W[i][0]; acc[2][1] += h4.z * W[i][1];
                acc[3][0] += h4.w * W[i][0]; acc[3][1] += h4.w * W[i][1];
            }
            // ---- DPP butterfly all-reduce over the 8 ks-lanes ----
            #pragma unroll
            for (int b = 0; b < 4; ++b)
                #pragma unroll
                for (int c = 0; c < 2; ++c) {
                    float v = acc[b][c];
                    v += DPPF(v, 0xB1);                  // xor 1
                    v += DPPF(v, 0x4E);                  // xor 2
                    v += DPPF(DPPF(v, 0x141), 0x1B);     // xor 4
                    acc[b][c] = v;
                }
            // lane ks writes value (b,c) = (ks>>1, ks&1)
            #pragma unroll
            for (int a = 0; a < 8; ++a)
                if (ks == a)
                    zbuf[(a >> 1) * 128 + gate * 32 + wg * 2 + (a & 1)] = acc[a >> 1][a & 1];
            __syncthreads();
        } else {
            zbuf[tid & 511] = 0.0f;
            __syncthreads();
        }
        // ---- phase 2: gates, state update, publish h ----
        if (tid < 128) {
            const float zi = zbuf[pb * 128 +      pd] + z0;
            const float zf = zbuf[pb * 128 + 32 + pd] + z1;
            const float zg = zbuf[pb * 128 + 64 + pd] + z2;
            const float zo = zbuf[pb * 128 + 96 + pd] + z3;
            c_state = sigf(zf) * c_state + sigf(zi) * tanhf_fast(zg);
            const float h = sigf(zo) * tanhf_fast(c_state);
            const int row = bt_layout ? (gb * 64 + t) : (t * 128 + gb);
            outbuf[(size_t)row * 512 + dir * 256 + dim] = h;
            __hip_atomic_store(
                &hx[(((size_t)(tt & 1)) * 2 + dir) * 32768 + (size_t)q * 1024 + pb * 256 + dim],
                h, __ATOMIC_RELAXED, __HIP_MEMORY_SCOPE_AGENT);
        }
        __syncthreads();  // vmcnt(0) drain: h stores complete before flag add
        if (tid == 0)
            __hip_atomic_fetch_add(&flags[fbase + tt], 1, __ATOMIC_RELAXED,
                                   __HIP_MEMORY_SCOPE_AGENT);
    }
}

// ---------------- attention pooling (unchanged) ----------------------------
__global__ __launch_bounds__(256) void k_attnpool(
    const float* __restrict__ hbar, const float* __restrict__ outp,
    const float* __restrict__ ws2, float* __restrict__ sent)
{
    __shared__ float hb[64][132];
    __shared__ float w2[8][128];
    __shared__ float att[8][64];
    const int b = blockIdx.x, tid = threadIdx.x;
    for (int i = tid; i < 1024; i += 256) ((float*)w2)[i] = ws2[i];
    const float* hsrc = hbar + (size_t)b * 64 * 128;
    for (int i = tid; i < 2048; i += 256) {
        const int row = i >> 5, d4 = (i & 31) << 2;
        *(float4*)&hb[row][d4] = *(const float4*)(hsrc + row * 128 + d4);
    }
    __syncthreads();
    for (int p = tid; p < 512; p += 256) {
        const int r = p >> 6, t = p & 63;
        float s = 0.0f;
        #pragma unroll 8
        for (int d = 0; d < 128; d += 4) {
            const float4 x = *(const float4*)&hb[t][d];
            const float4 y = *(const float4*)&w2[r][d];
            s += x.x * y.x + x.y * y.y + x.z * y.z + x.w * y.w;
        }
        att[r][t] = s;
    }
    __syncthreads();
    const float* ob = outp + (size_t)b * 64 * 512;
    float s0[8] = {}, s1[8] = {};
    for (int t = 0; t < 64; ++t) {
        const float v0 = ob[t * 512 + tid];
        const float v1 = ob[t * 512 + 256 + tid];
        #pragma unroll
        for (int r = 0; r < 8; ++r) {
            const float a = att[r][t];
            s0[r] += a * v0; s1[r] += a * v1;
        }
    }
    #pragma unroll
    for (int r = 0; r < 8; ++r) {
        sent[((size_t)b * 8 + r) * 512 + tid]       = s0[r];
        sent[((size_t)b * 8 + r) * 512 + 256 + tid] = s1[r];
    }
}

// ---------------- dynamic routing (unchanged) ------------------------------
__global__ __launch_bounds__(512) void k_routing(
    const float* __restrict__ votes, float* __restrict__ out)
{
    __shared__ float v[8][32][16];
    __shared__ float logits[8][32];
    __shared__ float route[8][32];
    const int b = blockIdx.x, tid = threadIdx.x;
    const float* vb = votes + (size_t)b * 4096;
    for (int i = tid; i < 4096; i += 512) ((float*)v)[i] = vb[i];
    if (tid < 256) ((float*)logits)[tid] = 0.0f;
    __syncthreads();
    const int c = tid >> 4, a = tid & 15;
    float n2 = 0.0f;
    for (int it = 0; it < 3; ++it) {
        if (tid < 256) {
            const int r = tid >> 5, cc = tid & 31;
            const float l = logits[r][cc];
            float mx = l;
            #pragma unroll
            for (int m = 1; m < 32; m <<= 1) mx = fmaxf(mx, __shfl_xor(mx, m));
            const float e = __expf(l - mx);
            float sm = e;
            #pragma unroll
            for (int m = 1; m < 32; m <<= 1) sm += __shfl_xor(sm, m);
            route[r][cc] = e / sm;
        }
        __syncthreads();
        float pa = 0.0f;
        #pragma unroll
        for (int r = 0; r < 8; ++r) pa += route[r][c] * v[r][c][a];
        n2 = pa * pa;
        #pragma unroll
        for (int m = 1; m < 16; m <<= 1) n2 += __shfl_xor(n2, m);
        const float nrm = sqrtf(n2);
        const float av = pa * (nrm / (0.5f + n2));
        if (it < 2) {
            #pragma unroll
            for (int r = 0; r < 8; ++r) {
                float u = v[r][c][a] * av;
                #pragma unroll
                for (int m = 1; m < 16; m <<= 1) u += __shfl_xor(u, m);
                if (a == 0) logits[r][c] += u;
            }
        }
        __syncthreads();
    }
    if (a == 0) out[b * 32 + c] = n2 / (0.5f + n2);
}

// ---------------------------------------------------------------------------
static void launch_scan(const float* Z, const float* wf, const float* wb,
                        float* ob, int bt, float* hx, int* fl, hipStream_t stream)
{
    int base0 = 0;
    void* args[] = {(void*)&Z, (void*)&wf, (void*)&wb, (void*)&ob,
                    (void*)&bt, (void*)&hx, (void*)&fl, (void*)&base0};
    if (hipLaunchCooperativeKernel((const void*)k_scan4, dim3(512), dim3(512),
                                   args, 0, stream) != hipSuccess) {
        // Fallback: two self-contained 256-block launches (dir0 then dir1).
        k_scan4<<<dim3(256), 512, 0, stream>>>(Z, wf, wb, ob, bt, hx, fl, 0);
        k_scan4<<<dim3(256), 512, 0, stream>>>(Z, wf, wb, ob, bt, hx, fl, 256);
    }
}

extern "C" void kernel_launch(void* const* d_in, const int* in_sizes, int n_in,
                              void* d_out, int out_size, void* d_ws, size_t ws_size,
                              hipStream_t stream) {
    (void)in_sizes; (void)n_in; (void)out_size; (void)ws_size;
    const int*   tokens  = (const int*)d_in[0];
    const float* emb     = (const float*)d_in[2];
    const float* w_ih_f0 = (const float*)d_in[3];
    const float* w_hh_f0 = (const float*)d_in[4];
    const float* b_f0    = (const float*)d_in[5];
    const float* w_ih_b0 = (const float*)d_in[6];
    const float* w_hh_b0 = (const float*)d_in[7];
    const float* b_b0    = (const float*)d_in[8];
    const float* w_ih_f1 = (const float*)d_in[9];
    const float* w_hh_f1 = (const float*)d_in[10];
    const float* b_f1    = (const float*)d_in[11];
    const float* w_ih_b1 = (const float*)d_in[12];
    const float* w_hh_b1 = (const float*)d_in[13];
    const float* b_b1    = (const float*)d_in[14];
    const float* ws1     = (const float*)d_in[15];
    const float* ws2     = (const float*)d_in[16];
    const float* caps    = (const float*)d_in[17];

    float* wsf  = (float*)d_ws;
    float* Wt   = wsf;                          //  4 * 262144
    float* Z    = Wt   + 4 * 262144;            //  8192*2048
    float* x1   = Z    + 16777216;              //  8192*512
    float* outp = x1   + 4194304;               //  8192*512
    float* hbar = outp + 4194304;               //  8192*128
    float* sent = hbar + 1048576;               //  128*8*512
    float* vote = sent + 524288;                //  128*8*512
    float* hx   = vote + 524288;                //  2*2*32*1024 = 131072
    int*   flags = (int*)(hx + 131072);         //  2 * 4096 ints
    float* out  = (float*)d_out;

    // 0. zero sync flags (every launch; replays don't re-poison)
    k_zero<<<dim3(32), 256, 0, stream>>>(flags, 8192);
    // 1. transpose recurrent weights
    k_transpose<<<dim3(32, 8, 4), dim3(32, 8), 0, stream>>>(w_hh_f0, w_hh_b0, w_hh_f1, w_hh_b1, Wt);
    // 2. layer-0 input projection (embedding gather fused)
    k_gemm<<<dim3(64, 16, 1), 256, 0, stream>>>(
        emb, 300, tokens, w_ih_f0, w_ih_b0, 1024, 300, b_f0, b_b0,
        Z, 2048, 300, 1, 0, 0LL, 0LL, 0LL);
    // 3. layer-0 scan -> x1 [t*128+b][512]
    launch_scan(Z, Wt, Wt + 262144, x1, 0, hx, flags, stream);
    // 4. layer-1 input projection
    k_gemm<<<dim3(64, 16, 1), 256, 0, stream>>>(
        x1, 512, (const int*)nullptr, w_ih_f1, w_ih_b1, 1024, 512, b_f1, b_b1,
        Z, 2048, 512, 1, 0, 0LL, 0LL, 0LL);
    // 5. layer-1 scan -> outp [b*64+t][512]
    launch_scan(Z, Wt + 2 * 262144, Wt + 3 * 262144, outp, 1, hx, flags + 4096, stream);
    // 6. hbar = tanh(outp @ ws1^T)
    k_gemm<<<dim3(64, 1, 1), 256, 0, stream>>>(
        outp, 512, (const int*)nullptr, ws1, (const float*)nullptr, 1 << 30, 512,
        (const float*)nullptr, (const float*)nullptr,
        hbar, 128, 512, 1, 1, 0LL, 0LL, 0LL);
    // 7. attention + sent
    k_attnpool<<<dim3(128), 256, 0, stream>>>(hbar, outp, ws2, sent);
    // 8. votes
    k_gemm<<<dim3(1, 4, 8), 256, 0, stream>>>(
        sent, 4096, (const int*)nullptr, caps, (const float*)nullptr, 1 << 30, 512,
        (const float*)nullptr, (const float*)nullptr,
        vote, 4096, 512, 0, 0, 512LL, 262144LL, 512LL);
    // 9. routing
    k_routing<<<dim3(128), 512, 0, stream>>>(vote, out);
}